// Round 14
// baseline (7738.188 us; speedup 1.0000x reference)
//
#include <hip/hip_runtime.h>
#include <math.h>

constexpr int cB = 64, cT = 600, cD = 512, cE = 640, cH = 1024, cA = 1024,
              cP = 1024, cV = 10025, cN = 64;
constexpr int cBT = cB * cT;       // 38400
constexpr int cKr = cH + cE + cD;  // 2176
constexpr int cM  = cB * cN;       // 4096
constexpr int cVp = 10112;         // V padded to 79*128
constexpr int cG3 = 3 * cH;        // 3072 (i,g,o)
constexpr int cTE = cT / 8;        // 75 rows per block (interleaved: tt = 8*i + od)
constexpr int cXCS = 516;          // xc stride: m, s, c[512], pad
constexpr int cNB = 8;             // blocks per batch

typedef __attribute__((ext_vector_type(8))) short bf16x8;
typedef __attribute__((ext_vector_type(4))) float f32x4;

__device__ __forceinline__ float bfu(unsigned short s) {
  return __uint_as_float(((unsigned int)s) << 16);
}
__device__ __forceinline__ unsigned short f2bf(float f) {
  unsigned int x = __float_as_uint(f);
  x += 0x7fffu + ((x >> 16) & 1u);
  return (unsigned short)(x >> 16);
}
__device__ __forceinline__ float fsig(float x) { return 1.0f / (1.0f + __expf(-x)); }
__device__ __forceinline__ float ftanh(float x) {
  float e = __expf(2.0f * x);
  return 1.0f - 2.0f / (e + 1.0f);
}

#define GLD(g, s)                                                          \
  __builtin_amdgcn_global_load_lds(                                       \
      (const __attribute__((address_space(1))) void*)(g),                 \
      (__attribute__((address_space(3))) void*)(s), 16, 0, 0)

__device__ __forceinline__ int xcd_swizzle(int bid, int nwg) {
  int q = nwg >> 3, r = nwg & 7;
  int x = bid & 7, loc = bid >> 3;
  return (x < r ? x * (q + 1) : r * (q + 1) + (x - r) * q) + loc;
}

// device-scope message passing (round-7-verified pattern)
__device__ __forceinline__ void ast(float* p, float v) {
  __hip_atomic_store(p, v, __ATOMIC_RELAXED, __HIP_MEMORY_SCOPE_AGENT);
}
__device__ __forceinline__ float ald(const float* p) {
  return __hip_atomic_load(p, __ATOMIC_RELAXED, __HIP_MEMORY_SCOPE_AGENT);
}
__device__ __forceinline__ void arrive_wait(unsigned* c, unsigned target) {
  __syncthreads();
  if (threadIdx.x == 0) {
    __hip_atomic_fetch_add(c, 1u, __ATOMIC_RELEASE, __HIP_MEMORY_SCOPE_AGENT);
    while (__hip_atomic_load(c, __ATOMIC_ACQUIRE, __HIP_MEMORY_SCOPE_AGENT) < target)
      __builtin_amdgcn_s_sleep(2);
  }
  __syncthreads();
}

// ---------------- precompute / casts ----------------

__global__ __launch_bounds__(256) void cast_kernel(const float* __restrict__ in,
                                                   unsigned short* __restrict__ out) {
  int i = blockIdx.x * 256 + threadIdx.x;
  float4 v = reinterpret_cast<const float4*>(in)[i];
  ushort4 o;
  o.x = f2bf(v.x); o.y = f2bf(v.y); o.z = f2bf(v.z); o.w = f2bf(v.w);
  reinterpret_cast<ushort4*>(out)[i] = o;
}

__global__ __launch_bounds__(256) void cast_hl_kernel(const float* __restrict__ in,
                                                      unsigned short* __restrict__ hi,
                                                      unsigned short* __restrict__ lo) {
  int i = blockIdx.x * 256 + threadIdx.x;
  float4 v = reinterpret_cast<const float4*>(in)[i];
  ushort4 h, l;
  h.x = f2bf(v.x); h.y = f2bf(v.y); h.z = f2bf(v.z); h.w = f2bf(v.w);
  l.x = f2bf(v.x - bfu(h.x)); l.y = f2bf(v.y - bfu(h.y));
  l.z = f2bf(v.z - bfu(h.z)); l.w = f2bf(v.w - bfu(h.w));
  reinterpret_cast<ushort4*>(hi)[i] = h;
  reinterpret_cast<ushort4*>(lo)[i] = l;
}

__global__ __launch_bounds__(256) void cast_wo_kernel(const float* __restrict__ in,
                                                      unsigned short* __restrict__ hi,
                                                      unsigned short* __restrict__ lo) {
  int idx = blockIdx.x * 256 + threadIdx.x;
  int row = idx >> 7;
  int k = (idx & 127) * 4;
  float4 v = (row < cV) ? *reinterpret_cast<const float4*>(&in[(size_t)row * cD + k])
                        : make_float4(0.f, 0.f, 0.f, 0.f);
  ushort4 h, l;
  h.x = f2bf(v.x); h.y = f2bf(v.y); h.z = f2bf(v.z); h.w = f2bf(v.w);
  l.x = f2bf(v.x - bfu(h.x)); l.y = f2bf(v.y - bfu(h.y));
  l.z = f2bf(v.z - bfu(h.z)); l.w = f2bf(v.w - bfu(h.w));
  reinterpret_cast<ushort4*>(hi)[idx] = h;
  reinterpret_cast<ushort4*>(lo)[idx] = l;
}

__global__ __launch_bounds__(256) void fert_kernel(const float* __restrict__ enc,
                                                   const float* __restrict__ W_fert,
                                                   float* __restrict__ inv_fert) {
  int wave = threadIdx.x >> 6, lane = threadIdx.x & 63;
  int row = blockIdx.x * 4 + wave;
  const float* r = enc + (size_t)row * cD;
  float s = 0.0f;
#pragma unroll
  for (int i = 0; i < 8; ++i) s += r[lane + 64 * i] * W_fert[lane + 64 * i];
#pragma unroll
  for (int o = 32; o; o >>= 1) s += __shfl_xor(s, o);
  if (lane == 0) inv_fert[row] = 1.0f / (1.0f + __expf(-s));
}

// shifted embeddings of labels -> hi/lo bf16 [4096][640]
__global__ __launch_bounds__(256) void build_aemb(const float* __restrict__ embed,
                                                  const int* __restrict__ labels,
                                                  unsigned short* __restrict__ Ah,
                                                  unsigned short* __restrict__ Al) {
  int idx = blockIdx.x * 256 + threadIdx.x;
  int row = idx / (cE / 4);
  int k = (idx % (cE / 4)) * 4;
  int b = row >> 6, tt = row & 63;
  float4 v = make_float4(0.f, 0.f, 0.f, 0.f);
  if (tt > 0) {
    int lab = labels[b * cN + tt - 1];
    v = *reinterpret_cast<const float4*>(&embed[(size_t)lab * cE + k]);
  }
  ushort4 h, l;
  h.x = f2bf(v.x); h.y = f2bf(v.y); h.z = f2bf(v.z); h.w = f2bf(v.w);
  l.x = f2bf(v.x - bfu(h.x)); l.y = f2bf(v.y - bfu(h.y));
  l.z = f2bf(v.z - bfu(h.z)); l.w = f2bf(v.w - bfu(h.w));
  *reinterpret_cast<ushort4*>(&Ah[(size_t)row * cE + k]) = h;
  *reinterpret_cast<ushort4*>(&Al[(size_t)row * cE + k]) = l;
}

// W_ih rows (i,g,o) x cols [0,640) -> hi/lo bf16 [3072][640] (for embg GEMM)
__global__ __launch_bounds__(256) void cast_wihe(const float* __restrict__ W_ih,
                                                 unsigned short* __restrict__ Wh,
                                                 unsigned short* __restrict__ Wl) {
  int idx = blockIdx.x * 256 + threadIdx.x;
  int jcol = idx / (cE / 4);
  int k = (idx % (cE / 4)) * 4;
  int r = (jcol < cH) ? jcol : jcol + cH;
  float4 v = *reinterpret_cast<const float4*>(&W_ih[(size_t)r * (cE + cD) + k]);
  ushort4 h, l;
  h.x = f2bf(v.x); h.y = f2bf(v.y); h.z = f2bf(v.z); h.w = f2bf(v.w);
  l.x = f2bf(v.x - bfu(h.x)); l.y = f2bf(v.y - bfu(h.y));
  l.z = f2bf(v.z - bfu(h.z)); l.w = f2bf(v.w - bfu(h.w));
  *reinterpret_cast<ushort4*>(&Wh[(size_t)jcol * cE + k]) = h;
  *reinterpret_cast<ushort4*>(&Wl[(size_t)jcol * cE + k]) = l;
}

// W_ih ctx-half -> packed k-major bf16: WihP[(k4*3072 + col)*4 + (k&3)]
__global__ __launch_bounds__(256) void pack_wih(const float* __restrict__ W_ih,
                                                unsigned short* __restrict__ WihP) {
  int idx = blockIdx.x * 256 + threadIdx.x;
  int col = idx >> 7;
  int k4 = idx & 127;
  int r = (col < cH) ? col : col + cH;
  float4 v = *reinterpret_cast<const float4*>(&W_ih[(size_t)r * (cE + cD) + cE + k4 * 4]);
  ushort4 h;
  h.x = f2bf(v.x); h.y = f2bf(v.y); h.z = f2bf(v.z); h.w = f2bf(v.w);
  *reinterpret_cast<ushort4*>(&WihP[((size_t)k4 * cG3 + col) * 4]) = h;
}

// W_s -> packed k-major bf16: WsP[(k4*1024 + a)*4 + (k&3)]
__global__ __launch_bounds__(256) void pack_ws(const float* __restrict__ W_s,
                                               unsigned short* __restrict__ WsP) {
  int idx = blockIdx.x * 256 + threadIdx.x;
  int a = idx >> 8;
  int k4 = idx & 255;
  float4 v = *reinterpret_cast<const float4*>(&W_s[(size_t)a * cH + k4 * 4]);
  ushort4 h;
  h.x = f2bf(v.x); h.y = f2bf(v.y); h.z = f2bf(v.z); h.w = f2bf(v.w);
  *reinterpret_cast<ushort4*>(&WsP[((size_t)k4 * cA + a) * 4]) = h;
}

// concat(s_seq, emb, ctx_seq) -> Ar hi/lo bf16 [4096][2176]
__global__ __launch_bounds__(256) void build_ar_kernel(
    const float* __restrict__ s_seq, const float* __restrict__ ctx_seq,
    const float* __restrict__ embed, const int* __restrict__ labels,
    unsigned short* __restrict__ Ah, unsigned short* __restrict__ Al) {
  int idx = blockIdx.x * 256 + threadIdx.x;
  int row = idx / (cKr / 4);
  int k = (idx % (cKr / 4)) * 4;
  int b = row >> 6, tt = row & 63;
  float4 v;
  if (k < cH) {
    v = *reinterpret_cast<const float4*>(&s_seq[(size_t)row * cH + k]);
  } else if (k < cH + cE) {
    if (tt == 0) {
      v = make_float4(0.f, 0.f, 0.f, 0.f);
    } else {
      int lab = labels[b * cN + tt - 1];
      v = *reinterpret_cast<const float4*>(&embed[(size_t)lab * cE + (k - cH)]);
    }
  } else {
    v = *reinterpret_cast<const float4*>(&ctx_seq[(size_t)row * cD + (k - cH - cE)]);
  }
  ushort4 h, l;
  h.x = f2bf(v.x); h.y = f2bf(v.y); h.z = f2bf(v.z); h.w = f2bf(v.w);
  l.x = f2bf(v.x - bfu(h.x)); l.y = f2bf(v.y - bfu(h.y));
  l.z = f2bf(v.z - bfu(h.z)); l.w = f2bf(v.w - bfu(h.w));
  *reinterpret_cast<ushort4*>(&Ah[(size_t)row * cKr + k]) = h;
  *reinterpret_cast<ushort4*>(&Al[(size_t)row * cKr + k]) = l;
}

// ---------------- MFMA GEMMs ----------------

// enc_ctx = enc_bf @ W_enc_bf^T + b_enc -> bf16 [38400][1024], PAIRED column layout:
// column c stored at position (c<512) ? 2c : 2(c-512)+1  (uint holds {a, a+512})
__global__ __launch_bounds__(256) void mfma_encctx(const unsigned short* __restrict__ A,
                                                   const unsigned short* __restrict__ Bm,
                                                   const float* __restrict__ bias,
                                                   unsigned short* __restrict__ C) {
  __shared__ unsigned short sA[4096], sB[4096];
  constexpr int nbx = cA / 128;
  int bid = xcd_swizzle(blockIdx.x, gridDim.x);
  int by = bid / nbx, bx = bid % nbx;
  int tid = threadIdx.x;
  int w = tid >> 6, l = tid & 63;
  int m0 = by * 128, n0 = bx * 128;
  int wr = w >> 1, wc = w & 1;
  f32x4 acc[4][4] = {};
  int srow = tid >> 2, scol = (tid & 3) * 8;
  for (int k0 = 0; k0 < cD; k0 += 32) {
    __syncthreads();
    GLD(&A[(size_t)(m0 + srow) * cD + k0 + scol], &sA[tid * 8]);
    GLD(&A[(size_t)(m0 + 64 + srow) * cD + k0 + scol], &sA[2048 + tid * 8]);
    GLD(&Bm[(size_t)(n0 + srow) * cD + k0 + scol], &sB[tid * 8]);
    GLD(&Bm[(size_t)(n0 + 64 + srow) * cD + k0 + scol], &sB[2048 + tid * 8]);
    __syncthreads();
    int rA = wr * 64 + (l & 15);
    int rB = wc * 64 + (l & 15);
    int kg = (l >> 4) * 8;
    bf16x8 a[4], b[4];
#pragma unroll
    for (int i = 0; i < 4; ++i) a[i] = *(const bf16x8*)&sA[(rA + i * 16) * 32 + kg];
#pragma unroll
    for (int j = 0; j < 4; ++j) b[j] = *(const bf16x8*)&sB[(rB + j * 16) * 32 + kg];
#pragma unroll
    for (int i = 0; i < 4; ++i)
#pragma unroll
      for (int j = 0; j < 4; ++j)
        acc[i][j] = __builtin_amdgcn_mfma_f32_16x16x32_bf16(a[i], b[j], acc[i][j], 0, 0, 0);
  }
  int rbase = m0 + wr * 64 + ((l >> 4) * 4);
  int cbase = n0 + wc * 64 + (l & 15);
  float bv[4];
#pragma unroll
  for (int j = 0; j < 4; ++j) bv[j] = bias[cbase + j * 16];
#pragma unroll
  for (int i = 0; i < 4; ++i)
#pragma unroll
    for (int q = 0; q < 4; ++q) {
      int row = rbase + i * 16 + q;
#pragma unroll
      for (int j = 0; j < 4; ++j) {
        int col = cbase + j * 16;
        int pos = (col < 512) ? (2 * col) : (2 * (col - 512) + 1);
        C[(size_t)row * cA + pos] = f2bf(acc[i][j][q] + bv[j]);
      }
    }
}

template <int EP>
__global__ __launch_bounds__(256) void mfma_gemm3(
    const unsigned short* __restrict__ Ah, const unsigned short* __restrict__ Al,
    const unsigned short* __restrict__ Bh, const unsigned short* __restrict__ Bl,
    const float* __restrict__ bias, void* __restrict__ outv, int K, int nbx) {
  __shared__ unsigned short sAh[4096], sAl[4096], sBh[4096], sBl[4096];
  int bid = xcd_swizzle(blockIdx.x, gridDim.x);
  int by = bid / nbx, bx = bid % nbx;
  int tid = threadIdx.x;
  int w = tid >> 6, l = tid & 63;
  int m0 = by * 128, n0 = bx * 128;
  int wr = w >> 1, wc = w & 1;
  f32x4 acc[4][4] = {};
  int srow = tid >> 2, scol = (tid & 3) * 8;
  for (int k0 = 0; k0 < K; k0 += 32) {
    __syncthreads();
    GLD(&Ah[(size_t)(m0 + srow) * K + k0 + scol], &sAh[tid * 8]);
    GLD(&Ah[(size_t)(m0 + 64 + srow) * K + k0 + scol], &sAh[2048 + tid * 8]);
    GLD(&Al[(size_t)(m0 + srow) * K + k0 + scol], &sAl[tid * 8]);
    GLD(&Al[(size_t)(m0 + 64 + srow) * K + k0 + scol], &sAl[2048 + tid * 8]);
    GLD(&Bh[(size_t)(n0 + srow) * K + k0 + scol], &sBh[tid * 8]);
    GLD(&Bh[(size_t)(n0 + 64 + srow) * K + k0 + scol], &sBh[2048 + tid * 8]);
    GLD(&Bl[(size_t)(n0 + srow) * K + k0 + scol], &sBl[tid * 8]);
    GLD(&Bl[(size_t)(n0 + 64 + srow) * K + k0 + scol], &sBl[2048 + tid * 8]);
    __syncthreads();
    int rA = wr * 64 + (l & 15);
    int rB = wc * 64 + (l & 15);
    int kg = (l >> 4) * 8;
    bf16x8 bh[4], bl[4];
#pragma unroll
    for (int j = 0; j < 4; ++j) {
      bh[j] = *(const bf16x8*)&sBh[(rB + j * 16) * 32 + kg];
      bl[j] = *(const bf16x8*)&sBl[(rB + j * 16) * 32 + kg];
    }
#pragma unroll
    for (int i = 0; i < 4; ++i) {
      bf16x8 ah = *(const bf16x8*)&sAh[(rA + i * 16) * 32 + kg];
      bf16x8 al = *(const bf16x8*)&sAl[(rA + i * 16) * 32 + kg];
#pragma unroll
      for (int j = 0; j < 4; ++j) {
        acc[i][j] = __builtin_amdgcn_mfma_f32_16x16x32_bf16(ah, bh[j], acc[i][j], 0, 0, 0);
        acc[i][j] = __builtin_amdgcn_mfma_f32_16x16x32_bf16(ah, bl[j], acc[i][j], 0, 0, 0);
        acc[i][j] = __builtin_amdgcn_mfma_f32_16x16x32_bf16(al, bh[j], acc[i][j], 0, 0, 0);
        if (EP == 2)
          acc[i][j] = __builtin_amdgcn_mfma_f32_16x16x32_bf16(al, bl[j], acc[i][j], 0, 0, 0);
      }
    }
  }
  int rbase = m0 + wr * 64 + ((l >> 4) * 4);
  int cbase = n0 + wc * 64 + (l & 15);
  if (EP == 0) {
    unsigned short* mo_h = (unsigned short*)outv;
    unsigned short* mo_l = mo_h + (size_t)cM * (cP / 2);
#pragma unroll
    for (int i = 0; i < 4; ++i)
#pragma unroll
      for (int q = 0; q < 4; ++q) {
        int row = rbase + i * 16 + q;
#pragma unroll
        for (int j = 0; j < 4; ++j) {
          float v = acc[i][j][q] + bias[cbase + j * 16];
          float o = fmaxf(v, __shfl_xor(v, 1));
          if (!(l & 1)) {
            int ch = (cbase + j * 16) >> 1;
            unsigned short h = f2bf(o);
            mo_h[(size_t)row * (cP / 2) + ch] = h;
            mo_l[(size_t)row * (cP / 2) + ch] = f2bf(o - bfu(h));
          }
        }
      }
  } else if (EP == 1) {
    float* out = (float*)outv;
#pragma unroll
    for (int i = 0; i < 4; ++i)
#pragma unroll
      for (int q = 0; q < 4; ++q) {
        int row = rbase + i * 16 + q;
#pragma unroll
        for (int j = 0; j < 4; ++j) {
          int col = cbase + j * 16;
          if (col < cV) out[(size_t)row * cV + col] = acc[i][j][q] + bias[col];
        }
      }
  } else {
    float* out = (float*)outv;  // embg [4096 rows][3072]
#pragma unroll
    for (int i = 0; i < 4; ++i)
#pragma unroll
      for (int q = 0; q < 4; ++q) {
        int row = rbase + i * 16 + q;
#pragma unroll
        for (int j = 0; j < 4; ++j)
          out[(size_t)row * cG3 + cbase + j * 16] = acc[i][j][q];
      }
  }
}

// ---------------- split fused loop: 8 blocks/batch, 2 blocks/CU, prefetched streams ----------------

struct LoopArgs {
  const unsigned short* enc_ctx;  // bf16 [38400][1024] paired-column layout
  const unsigned short* enc_bf;   // bf16 [38400][512]
  const unsigned short* WihP;     // packed [128][3072][4] bf16 (k-major)
  const unsigned short* WsP;      // packed [256][1024][4] bf16 (k-major)
  const float* b_ih;
  const float* b_hh;
  const float* embg;              // fp32 [4096][3072]
  const float* inv_fert;          // [38400]
  const float* v_att;
  const float* W_fb;
  const int* slen;
  float* s_seq;                   // [4096][1024]
  float* ctx_seq;                 // [4096][512]
  float* xq;                      // [2][64][8][1024] q partials
  float* xc;                      // [2][64][8][516] softmax partials
  unsigned* cnt;                  // [2][64][64] arrival counters (256B stride)
};

__global__ __launch_bounds__(1024, 8)  // 8 waves/EU => 2 blocks/CU co-resident, VGPR<=64
void split_loop(LoopArgs A) {
  __shared__ float ctx_s[cD];
  __shared__ float h_s[128];       // own j-eighth of h
  __shared__ float q_s[cA];
  __shared__ float ew_s[cTE + 5];  // pads [75..79] stay 0
  __shared__ float acc_s[cTE];
  __shared__ float fert_s[cTE];
  __shared__ float vatt_s[cA];
  __shared__ float wfb_s[cA];
  __shared__ float cpartL[4][256];
  __shared__ float cpartH[4][256];
  __shared__ float red_s[16];
  __shared__ float ms_s[16];       // (m,s) of the 8 eighths

  const int od = blockIdx.x & 7;              // eighth 0..7 (same-od -> same XCD)
  const int b = blockIdx.x >> 3;              // batch 0..63
  const int tid = threadIdx.x;
  const int wv = tid >> 6, ln = tid & 63;     // 16 waves
  const int jl = tid >> 3, part = tid & 7;    // 128 j x 8 k-parts
  const int gp = tid >> 8, pp = tid & 255;    // P4: row-group x d-pair
  const int j0 = od * 128;
  const int len = A.slen[b];
  const int nv = (len - od + 7) >> 3;         // valid rows for this block (i < nv)
  unsigned* cntQ = A.cnt + (0 * cB + b) * 64;
  unsigned* cntS = A.cnt + (1 * cB + b) * 64;

  // init
  if (tid < cD) ctx_s[tid] = 0.f;
  vatt_s[tid] = A.v_att[tid];
  wfb_s[tid] = A.W_fb[tid];
  if (tid < cTE) {
    acc_s[tid] = 0.f;
    fert_s[tid] = A.inv_fert[b * cT + 8 * tid + od];
  }
  if (tid >= cTE && tid < cTE + 5) ew_s[tid] = 0.f;  // pads, never rewritten
  float h_my = 0.f, bgi = 0.f, bgg = 0.f, bgo = 0.f;
  if (part == 0) {
    int j = j0 + jl;
    bgi = A.b_ih[j] + A.b_hh[j];
    bgg = A.b_ih[j + 2048] + A.b_hh[j + 2048];
    bgo = A.b_ih[j + 3072] + A.b_hh[j + 3072];
  }
  __syncthreads();

  for (int t = 0; t < cN; ++t) {
    const int par = t & 1;
    const unsigned tgt = (unsigned)cNB * (t + 1);

    // ---- P1: h for j-eighth (8-lane k-split over 512 ctx dims) ----
    {
      float ai = 0.f, ag = 0.f, ao = 0.f;
      const unsigned short* wbase = A.WihP + (size_t)(j0 + jl) * 4;
#pragma unroll 4
      for (int k4 = 0; k4 < 16; ++k4) {
        int kk = (k4 + 2 * part) & 15;           // stagger: 2-way max on LDS banks
        int row = part * 16 + kk;
        float4 c = *reinterpret_cast<const float4*>(&ctx_s[row * 4]);
        const unsigned short* pw = wbase + (size_t)row * (cG3 * 4);
        ushort4 wi = *reinterpret_cast<const ushort4*>(pw);
        ushort4 wg = *reinterpret_cast<const ushort4*>(pw + (size_t)1024 * 4);
        ushort4 wo = *reinterpret_cast<const ushort4*>(pw + (size_t)2048 * 4);
        ai += bfu(wi.x) * c.x + bfu(wi.y) * c.y + bfu(wi.z) * c.z + bfu(wi.w) * c.w;
        ag += bfu(wg.x) * c.x + bfu(wg.y) * c.y + bfu(wg.z) * c.z + bfu(wg.w) * c.w;
        ao += bfu(wo.x) * c.x + bfu(wo.y) * c.y + bfu(wo.z) * c.z + bfu(wo.w) * c.w;
      }
      ai += __shfl_xor(ai, 1); ai += __shfl_xor(ai, 2); ai += __shfl_xor(ai, 4);
      ag += __shfl_xor(ag, 1); ag += __shfl_xor(ag, 2); ag += __shfl_xor(ag, 4);
      ao += __shfl_xor(ao, 1); ao += __shfl_xor(ao, 2); ao += __shfl_xor(ao, 4);
      if (part == 0) {
        int j = j0 + jl;
        const float* eg = A.embg + (size_t)(b * cN + t) * cG3;
        float gi = ai + bgi + eg[j];
        float gg = ag + bgg + eg[j + 1024];
        float go = ao + bgo + eg[j + 2048];
        float hnew = fsig(go) * ftanh(fsig(gi) * ftanh(gg));
        h_my = 0.05f * h_my + 0.95f * hnew;
        A.s_seq[(size_t)(b * cN + t) * cH + j] = h_my;
        h_s[jl] = h_my;
      }
    }
    __syncthreads();

    // ---- P2: partial q over ALL 1024 a from own 128-k slice ----
    {
      float aq = 0.f;
      const unsigned short* pw = A.WsP + ((size_t)(od * 32) * cA + tid) * 4;
#pragma unroll 8
      for (int kk = 0; kk < 32; ++kk) {
        float4 hh = *reinterpret_cast<const float4*>(&h_s[kk * 4]);
        ushort4 w = *reinterpret_cast<const ushort4*>(pw);
        aq += bfu(w.x) * hh.x + bfu(w.y) * hh.y + bfu(w.z) * hh.z + bfu(w.w) * hh.w;
        pw += (size_t)cA * 4;
      }
      ast(&A.xq[(((size_t)par * cB + b) * cNB + od) * cA + tid], aq);
    }
    arrive_wait(cntQ, tgt);
    {
      const float* xb = A.xq + ((size_t)par * cB + b) * cNB * cA;
      float s = 0.f;
#pragma unroll
      for (int o = 0; o < cNB; ++o) s += ald(&xb[o * cA + tid]);
      q_s[tid] = s;
    }
    __syncthreads();

    // ---- P3: energies, double-buffered row prefetch (rows i = wv + 16*ip) ----
    {
      unsigned bufA[8], bufB[8];
      if (wv < nv) {
        const unsigned* rp =
            (const unsigned*)(A.enc_ctx + (size_t)(b * cT + 8 * wv + od) * cA);
#pragma unroll
        for (int k2 = 0; k2 < 8; ++k2) bufA[k2] = rp[ln + 64 * k2];
      }
#pragma unroll
      for (int ip = 0; ip < 5; ++ip) {
        int i = wv + 16 * ip;
        int in2 = i + 16;
        if (ip < 4 && in2 < nv) {
          const unsigned* rp =
              (const unsigned*)(A.enc_ctx + (size_t)(b * cT + 8 * in2 + od) * cA);
          if ((ip & 1) == 0) {
#pragma unroll
            for (int k2 = 0; k2 < 8; ++k2) bufB[k2] = rp[ln + 64 * k2];
          } else {
#pragma unroll
            for (int k2 = 0; k2 < 8; ++k2) bufA[k2] = rp[ln + 64 * k2];
          }
        }
        if (i < nv) {
          float fb = acc_s[i];
          float acc = 0.f;
#pragma unroll
          for (int k2 = 0; k2 < 8; ++k2) {
            unsigned u = ((ip & 1) == 0) ? bufA[k2] : bufB[k2];
            int a0 = ln + 64 * k2;
            float c0 = __uint_as_float(u << 16);
            float c1 = __uint_as_float(u & 0xffff0000u);
            acc += vatt_s[a0] * ftanh(c0 + q_s[a0] + fb * wfb_s[a0]);
            acc += vatt_s[a0 + 512] * ftanh(c1 + q_s[a0 + 512] + fb * wfb_s[a0 + 512]);
          }
#pragma unroll
          for (int o = 32; o; o >>= 1) acc += __shfl_xor(acc, o);
          if (ln == 0) ew_s[i] = acc;
        } else if (i < cTE) {
          if (ln == 0) ew_s[i] = -__builtin_inff();
        }
      }
    }
    __syncthreads();

    // ---- local softmax over own rows ----
    float m_loc;
    {
      float m = (tid < cTE) ? ew_s[tid] : -__builtin_inff();
#pragma unroll
      for (int o = 32; o; o >>= 1) m = fmaxf(m, __shfl_xor(m, o));
      if (ln == 0) red_s[wv] = m;
      __syncthreads();
      m = red_s[0];
#pragma unroll
      for (int w2 = 1; w2 < 16; ++w2) m = fmaxf(m, red_s[w2]);
      m_loc = m;
      __syncthreads();
      float wn = 0.f;
      if (tid < cTE) {
        float e = ew_s[tid];
        if (e > -__builtin_inff()) wn = __expf(e - m_loc);
        ew_s[tid] = wn;
      }
      float sp = wn;
#pragma unroll
      for (int o = 32; o; o >>= 1) sp += __shfl_xor(sp, o);
      if (ln == 0) red_s[wv] = sp;
      __syncthreads();
    }
    float s_loc = red_s[0];
#pragma unroll
    for (int w2 = 1; w2 < 16; ++w2) s_loc += red_s[w2];
    __syncthreads();

    // ---- partial ctx over VALID rows only (streamed enc_bf) ----
    {
      float s0 = 0.f, s1 = 0.f;
#pragma unroll
      for (int ii = 0; ii < 19; ++ii) {
        int i = gp + 4 * ii;
        if (i < nv) {                           // len-bounded: skip masked tail
          float wgt = ew_s[i];
          unsigned u =
              ((const unsigned*)(A.enc_bf + ((size_t)b * cT + 8 * i + od) * cD))[pp];
          s0 += wgt * __uint_as_float(u << 16);
          s1 += wgt * __uint_as_float(u & 0xffff0000u);
        }
      }
      cpartL[gp][pp] = s0;
      cpartH[gp][pp] = s1;
    }
    __syncthreads();
    {
      float* xcb = A.xc + (((size_t)par * cB + b) * cNB + od) * cXCS;
      if (tid < cD) {
        int p2 = tid >> 1;
        float v = (tid & 1)
                      ? (cpartH[0][p2] + cpartH[1][p2] + cpartH[2][p2] + cpartH[3][p2])
                      : (cpartL[0][p2] + cpartL[1][p2] + cpartL[2][p2] + cpartL[3][p2]);
        ast(&xcb[2 + tid], v);
      }
      if (tid == 0) ast(&xcb[0], m_loc);
      if (tid == 1) ast(&xcb[1], s_loc);
    }
    arrive_wait(cntS, tgt);

    // ---- combine: M, tot, full ctx; accum update ----
    if (tid < 16) {
      ms_s[tid] =
          ald(&A.xc[(((size_t)par * cB + b) * cNB + (tid >> 1)) * cXCS + (tid & 1)]);
    }
    __syncthreads();
    {
      float M = -__builtin_inff();
#pragma unroll
      for (int o = 0; o < cNB; ++o) M = fmaxf(M, ms_s[2 * o]);
      float tot = 0.f;
      float sc[cNB];
#pragma unroll
      for (int o = 0; o < cNB; ++o) {
        sc[o] = __expf(ms_s[2 * o] - M);
        tot += ms_s[2 * o + 1] * sc[o];
      }
      float invt = 1.0f / tot;
      if (tid < cD) {
        const float* xcb = A.xc + ((size_t)par * cB + b) * cNB * cXCS;
        float cv = 0.f;
#pragma unroll
        for (int o = 0; o < cNB; ++o) cv += ald(&xcb[o * cXCS + 2 + tid]) * sc[o];
        cv *= invt;
        ctx_s[tid] = cv;
        if (od == 0) A.ctx_seq[(size_t)(b * cN + t) * cD + tid] = cv;
      } else {
        int i = tid - 512;
        if (i < cTE) {
          float scq = __expf(m_loc - M);
          acc_s[i] += ew_s[i] * scq * invt * fert_s[i] * 0.5f;
        }
      }
    }
    __syncthreads();
  }
}

// ---------------- launcher ----------------

extern "C" void kernel_launch(void* const* d_in, const int* in_sizes, int n_in,
                              void* d_out, int out_size, void* d_ws, size_t ws_size,
                              hipStream_t stream) {
  (void)in_sizes; (void)n_in; (void)out_size; (void)ws_size;
  const float* enc    = (const float*)d_in[0];
  const int*   labels = (const int*)d_in[1];
  const int*   slen   = (const int*)d_in[2];
  const float* embed  = (const float*)d_in[3];
  const float* W_ih   = (const float*)d_in[4];
  const float* b_ih   = (const float*)d_in[5];
  const float* b_hh   = (const float*)d_in[6];
  const float* W_s    = (const float*)d_in[7];
  const float* W_enc  = (const float*)d_in[8];
  const float* b_enc  = (const float*)d_in[9];
  const float* v_att  = (const float*)d_in[10];
  const float* W_fert = (const float*)d_in[11];
  const float* W_fb   = (const float*)d_in[12];
  const float* W_r    = (const float*)d_in[13];
  const float* b_r    = (const float*)d_in[14];
  const float* W_o    = (const float*)d_in[15];
  const float* b_o    = (const float*)d_in[16];
  float* out = (float*)d_out;

  char* ws = (char*)d_ws;
  size_t off = 0;
  auto alloc = [&](size_t bytes) -> char* {
    char* p = ws + off;
    off = (off + bytes + 255) & ~(size_t)255;
    return p;
  };
  unsigned short* enc_ctx = (unsigned short*)alloc((size_t)cBT * cA * 2);
  unsigned short* enc_bf  = (unsigned short*)alloc((size_t)cBT * cD * 2);
  unsigned short* wencb   = (unsigned short*)alloc((size_t)cA * cD * 2);
  float* inv_fert = (float*)alloc((size_t)cBT * 4);
  unsigned short* WihP = (unsigned short*)alloc((size_t)cD * cG3 * 2);
  unsigned short* WsP  = (unsigned short*)alloc((size_t)cH * cA * 2);
  float* embg     = (float*)alloc((size_t)cM * cG3 * 4);
  float* s_seq    = (float*)alloc((size_t)cM * cH * 4);
  float* ctx_seq  = (float*)alloc((size_t)cM * cD * 4);
  float* xq       = (float*)alloc((size_t)2 * cB * cNB * cA * 4);
  float* xc       = (float*)alloc((size_t)2 * cB * cNB * cXCS * 4);
  unsigned* cnt   = (unsigned*)alloc((size_t)2 * cB * 64 * 4);
  unsigned short* Aemb_h = (unsigned short*)alloc((size_t)cM * cE * 2);
  unsigned short* Aemb_l = (unsigned short*)alloc((size_t)cM * cE * 2);
  unsigned short* Wihe_h = (unsigned short*)alloc((size_t)cG3 * cE * 2);
  unsigned short* Wihe_l = (unsigned short*)alloc((size_t)cG3 * cE * 2);
  unsigned short* Ar_h = (unsigned short*)alloc((size_t)cM * cKr * 2);
  unsigned short* Ar_l = (unsigned short*)alloc((size_t)cM * cKr * 2);
  unsigned short* Wr_h = (unsigned short*)alloc((size_t)cP * cKr * 2);
  unsigned short* Wr_l = (unsigned short*)alloc((size_t)cP * cKr * 2);
  unsigned short* mo_hl = (unsigned short*)alloc((size_t)2 * cM * (cP / 2) * 2);
  unsigned short* Wo_h = (unsigned short*)alloc((size_t)cVp * cD * 2);
  unsigned short* Wo_l = (unsigned short*)alloc((size_t)cVp * cD * 2);

  hipMemsetAsync(cnt, 0, (size_t)2 * cB * 64 * 4, stream);

  cast_kernel<<<(cBT * cD) / 1024, 256, 0, stream>>>(enc, enc_bf);
  cast_kernel<<<(cA * cD) / 1024, 256, 0, stream>>>(W_enc, wencb);
  fert_kernel<<<cBT / 4, 256, 0, stream>>>(enc, W_fert, inv_fert);
  mfma_encctx<<<(cBT / 128) * (cA / 128), 256, 0, stream>>>(enc_bf, wencb, b_enc, enc_ctx);
  build_aemb<<<(cM * cE / 4) / 256, 256, 0, stream>>>(embed, labels, Aemb_h, Aemb_l);
  cast_wihe<<<(cG3 * cE / 4) / 256, 256, 0, stream>>>(W_ih, Wihe_h, Wihe_l);
  pack_wih<<<(cG3 * (cD / 4)) / 256, 256, 0, stream>>>(W_ih, WihP);
  pack_ws<<<(cA * (cH / 4)) / 256, 256, 0, stream>>>(W_s, WsP);
  cast_hl_kernel<<<(cP * cKr) / 1024, 256, 0, stream>>>(W_r, Wr_h, Wr_l);
  cast_wo_kernel<<<(cVp * cD) / 1024, 256, 0, stream>>>(W_o, Wo_h, Wo_l);
  mfma_gemm3<2><<<(cM / 128) * (cG3 / 128), 256, 0, stream>>>(
      Aemb_h, Aemb_l, Wihe_h, Wihe_l, nullptr, (void*)embg, cE, cG3 / 128);

  LoopArgs la;
  la.enc_ctx = enc_ctx; la.enc_bf = enc_bf; la.WihP = WihP; la.WsP = WsP;
  la.b_ih = b_ih; la.b_hh = b_hh; la.embg = embg; la.inv_fert = inv_fert;
  la.v_att = v_att; la.W_fb = W_fb; la.slen = slen;
  la.s_seq = s_seq; la.ctx_seq = ctx_seq;
  la.xq = xq; la.xc = xc; la.cnt = cnt;
  split_loop<<<dim3(cB * cNB), dim3(1024), 0, stream>>>(la);

  build_ar_kernel<<<(cM * cKr) / 1024, 256, 0, stream>>>(s_seq, ctx_seq, embed, labels,
                                                         Ar_h, Ar_l);
  mfma_gemm3<0><<<(cM / 128) * (cP / 128), 256, 0, stream>>>(Ar_h, Ar_l, Wr_h, Wr_l, b_r,
                                                             (void*)mo_hl, cKr, cP / 128);
  unsigned short* mo_h = mo_hl;
  unsigned short* mo_l = mo_hl + (size_t)cM * (cP / 2);
  mfma_gemm3<1><<<(cM / 128) * (cVp / 128), 256, 0, stream>>>(mo_h, mo_l, Wo_h, Wo_l, b_o,
                                                              (void*)out, cP / 2, cVp / 128);
}

// Round 15
// 7269.762 us; speedup vs baseline: 1.0644x; 1.0644x over previous
//
#include <hip/hip_runtime.h>
#include <math.h>

constexpr int cB = 64, cT = 600, cD = 512, cE = 640, cH = 1024, cA = 1024,
              cP = 1024, cV = 10025, cN = 64;
constexpr int cBT = cB * cT;       // 38400
constexpr int cKr = cH + cE + cD;  // 2176
constexpr int cM  = cB * cN;       // 4096
constexpr int cVp = 10112;         // V padded to 79*128
constexpr int cG3 = 3 * cH;        // 3072 (i,g,o)
constexpr int cTE = cT / 8;        // 75 rows per block (interleaved: tt = 8*i + od)
constexpr int cXCS = 516;          // xc stride: m, s, c[512], pad
constexpr int cNB = 8;             // blocks per batch

typedef __attribute__((ext_vector_type(8))) short bf16x8;
typedef __attribute__((ext_vector_type(4))) float f32x4;

__device__ __forceinline__ float bfu(unsigned short s) {
  return __uint_as_float(((unsigned int)s) << 16);
}
__device__ __forceinline__ unsigned short f2bf(float f) {
  unsigned int x = __float_as_uint(f);
  x += 0x7fffu + ((x >> 16) & 1u);
  return (unsigned short)(x >> 16);
}
__device__ __forceinline__ float fsig(float x) { return 1.0f / (1.0f + __expf(-x)); }
__device__ __forceinline__ float ftanh(float x) {
  float e = __expf(2.0f * x);
  return 1.0f - 2.0f / (e + 1.0f);
}

#define GLD(g, s)                                                          \
  __builtin_amdgcn_global_load_lds(                                       \
      (const __attribute__((address_space(1))) void*)(g),                 \
      (__attribute__((address_space(3))) void*)(s), 16, 0, 0)

__device__ __forceinline__ int xcd_swizzle(int bid, int nwg) {
  int q = nwg >> 3, r = nwg & 7;
  int x = bid & 7, loc = bid >> 3;
  return (x < r ? x * (q + 1) : r * (q + 1) + (x - r) * q) + loc;
}

// device-scope message passing (round-7-verified pattern)
__device__ __forceinline__ void ast(float* p, float v) {
  __hip_atomic_store(p, v, __ATOMIC_RELAXED, __HIP_MEMORY_SCOPE_AGENT);
}
__device__ __forceinline__ float ald(const float* p) {
  return __hip_atomic_load(p, __ATOMIC_RELAXED, __HIP_MEMORY_SCOPE_AGENT);
}
__device__ __forceinline__ void arrive_wait(unsigned* c, unsigned target) {
  __syncthreads();
  if (threadIdx.x == 0) {
    __hip_atomic_fetch_add(c, 1u, __ATOMIC_RELEASE, __HIP_MEMORY_SCOPE_AGENT);
    while (__hip_atomic_load(c, __ATOMIC_ACQUIRE, __HIP_MEMORY_SCOPE_AGENT) < target)
      __builtin_amdgcn_s_sleep(2);
  }
  __syncthreads();
}

// ---------------- precompute / casts ----------------

__global__ __launch_bounds__(256) void cast_kernel(const float* __restrict__ in,
                                                   unsigned short* __restrict__ out) {
  int i = blockIdx.x * 256 + threadIdx.x;
  float4 v = reinterpret_cast<const float4*>(in)[i];
  ushort4 o;
  o.x = f2bf(v.x); o.y = f2bf(v.y); o.z = f2bf(v.z); o.w = f2bf(v.w);
  reinterpret_cast<ushort4*>(out)[i] = o;
}

__global__ __launch_bounds__(256) void cast_hl_kernel(const float* __restrict__ in,
                                                      unsigned short* __restrict__ hi,
                                                      unsigned short* __restrict__ lo) {
  int i = blockIdx.x * 256 + threadIdx.x;
  float4 v = reinterpret_cast<const float4*>(in)[i];
  ushort4 h, l;
  h.x = f2bf(v.x); h.y = f2bf(v.y); h.z = f2bf(v.z); h.w = f2bf(v.w);
  l.x = f2bf(v.x - bfu(h.x)); l.y = f2bf(v.y - bfu(h.y));
  l.z = f2bf(v.z - bfu(h.z)); l.w = f2bf(v.w - bfu(h.w));
  reinterpret_cast<ushort4*>(hi)[i] = h;
  reinterpret_cast<ushort4*>(lo)[i] = l;
}

__global__ __launch_bounds__(256) void cast_wo_kernel(const float* __restrict__ in,
                                                      unsigned short* __restrict__ hi,
                                                      unsigned short* __restrict__ lo) {
  int idx = blockIdx.x * 256 + threadIdx.x;
  int row = idx >> 7;
  int k = (idx & 127) * 4;
  float4 v = (row < cV) ? *reinterpret_cast<const float4*>(&in[(size_t)row * cD + k])
                        : make_float4(0.f, 0.f, 0.f, 0.f);
  ushort4 h, l;
  h.x = f2bf(v.x); h.y = f2bf(v.y); h.z = f2bf(v.z); h.w = f2bf(v.w);
  l.x = f2bf(v.x - bfu(h.x)); l.y = f2bf(v.y - bfu(h.y));
  l.z = f2bf(v.z - bfu(h.z)); l.w = f2bf(v.w - bfu(h.w));
  reinterpret_cast<ushort4*>(hi)[idx] = h;
  reinterpret_cast<ushort4*>(lo)[idx] = l;
}

__global__ __launch_bounds__(256) void fert_kernel(const float* __restrict__ enc,
                                                   const float* __restrict__ W_fert,
                                                   float* __restrict__ inv_fert) {
  int wave = threadIdx.x >> 6, lane = threadIdx.x & 63;
  int row = blockIdx.x * 4 + wave;
  const float* r = enc + (size_t)row * cD;
  float s = 0.0f;
#pragma unroll
  for (int i = 0; i < 8; ++i) s += r[lane + 64 * i] * W_fert[lane + 64 * i];
#pragma unroll
  for (int o = 32; o; o >>= 1) s += __shfl_xor(s, o);
  if (lane == 0) inv_fert[row] = 1.0f / (1.0f + __expf(-s));
}

// shifted embeddings of labels -> hi/lo bf16 [4096][640]
__global__ __launch_bounds__(256) void build_aemb(const float* __restrict__ embed,
                                                  const int* __restrict__ labels,
                                                  unsigned short* __restrict__ Ah,
                                                  unsigned short* __restrict__ Al) {
  int idx = blockIdx.x * 256 + threadIdx.x;
  int row = idx / (cE / 4);
  int k = (idx % (cE / 4)) * 4;
  int b = row >> 6, tt = row & 63;
  float4 v = make_float4(0.f, 0.f, 0.f, 0.f);
  if (tt > 0) {
    int lab = labels[b * cN + tt - 1];
    v = *reinterpret_cast<const float4*>(&embed[(size_t)lab * cE + k]);
  }
  ushort4 h, l;
  h.x = f2bf(v.x); h.y = f2bf(v.y); h.z = f2bf(v.z); h.w = f2bf(v.w);
  l.x = f2bf(v.x - bfu(h.x)); l.y = f2bf(v.y - bfu(h.y));
  l.z = f2bf(v.z - bfu(h.z)); l.w = f2bf(v.w - bfu(h.w));
  *reinterpret_cast<ushort4*>(&Ah[(size_t)row * cE + k]) = h;
  *reinterpret_cast<ushort4*>(&Al[(size_t)row * cE + k]) = l;
}

// W_ih rows (i,g,o) x cols [0,640) -> hi/lo bf16 [3072][640] (for embg GEMM)
__global__ __launch_bounds__(256) void cast_wihe(const float* __restrict__ W_ih,
                                                 unsigned short* __restrict__ Wh,
                                                 unsigned short* __restrict__ Wl) {
  int idx = blockIdx.x * 256 + threadIdx.x;
  int jcol = idx / (cE / 4);
  int k = (idx % (cE / 4)) * 4;
  int r = (jcol < cH) ? jcol : jcol + cH;
  float4 v = *reinterpret_cast<const float4*>(&W_ih[(size_t)r * (cE + cD) + k]);
  ushort4 h, l;
  h.x = f2bf(v.x); h.y = f2bf(v.y); h.z = f2bf(v.z); h.w = f2bf(v.w);
  l.x = f2bf(v.x - bfu(h.x)); l.y = f2bf(v.y - bfu(h.y));
  l.z = f2bf(v.z - bfu(h.z)); l.w = f2bf(v.w - bfu(h.w));
  *reinterpret_cast<ushort4*>(&Wh[(size_t)jcol * cE + k]) = h;
  *reinterpret_cast<ushort4*>(&Wl[(size_t)jcol * cE + k]) = l;
}

// W_ih ctx-half -> packed k-major bf16: WihP[(k4*3072 + col)*4 + (k&3)]
__global__ __launch_bounds__(256) void pack_wih(const float* __restrict__ W_ih,
                                                unsigned short* __restrict__ WihP) {
  int idx = blockIdx.x * 256 + threadIdx.x;
  int col = idx >> 7;
  int k4 = idx & 127;
  int r = (col < cH) ? col : col + cH;
  float4 v = *reinterpret_cast<const float4*>(&W_ih[(size_t)r * (cE + cD) + cE + k4 * 4]);
  ushort4 h;
  h.x = f2bf(v.x); h.y = f2bf(v.y); h.z = f2bf(v.z); h.w = f2bf(v.w);
  *reinterpret_cast<ushort4*>(&WihP[((size_t)k4 * cG3 + col) * 4]) = h;
}

// W_s -> packed k-major bf16: WsP[(k4*1024 + a)*4 + (k&3)]
__global__ __launch_bounds__(256) void pack_ws(const float* __restrict__ W_s,
                                               unsigned short* __restrict__ WsP) {
  int idx = blockIdx.x * 256 + threadIdx.x;
  int a = idx >> 8;
  int k4 = idx & 255;
  float4 v = *reinterpret_cast<const float4*>(&W_s[(size_t)a * cH + k4 * 4]);
  ushort4 h;
  h.x = f2bf(v.x); h.y = f2bf(v.y); h.z = f2bf(v.z); h.w = f2bf(v.w);
  *reinterpret_cast<ushort4*>(&WsP[((size_t)k4 * cA + a) * 4]) = h;
}

// concat(s_seq, emb, ctx_seq) -> Ar hi/lo bf16 [4096][2176]
__global__ __launch_bounds__(256) void build_ar_kernel(
    const float* __restrict__ s_seq, const float* __restrict__ ctx_seq,
    const float* __restrict__ embed, const int* __restrict__ labels,
    unsigned short* __restrict__ Ah, unsigned short* __restrict__ Al) {
  int idx = blockIdx.x * 256 + threadIdx.x;
  int row = idx / (cKr / 4);
  int k = (idx % (cKr / 4)) * 4;
  int b = row >> 6, tt = row & 63;
  float4 v;
  if (k < cH) {
    v = *reinterpret_cast<const float4*>(&s_seq[(size_t)row * cH + k]);
  } else if (k < cH + cE) {
    if (tt == 0) {
      v = make_float4(0.f, 0.f, 0.f, 0.f);
    } else {
      int lab = labels[b * cN + tt - 1];
      v = *reinterpret_cast<const float4*>(&embed[(size_t)lab * cE + (k - cH)]);
    }
  } else {
    v = *reinterpret_cast<const float4*>(&ctx_seq[(size_t)row * cD + (k - cH - cE)]);
  }
  ushort4 h, l;
  h.x = f2bf(v.x); h.y = f2bf(v.y); h.z = f2bf(v.z); h.w = f2bf(v.w);
  l.x = f2bf(v.x - bfu(h.x)); l.y = f2bf(v.y - bfu(h.y));
  l.z = f2bf(v.z - bfu(h.z)); l.w = f2bf(v.w - bfu(h.w));
  *reinterpret_cast<ushort4*>(&Ah[(size_t)row * cKr + k]) = h;
  *reinterpret_cast<ushort4*>(&Al[(size_t)row * cKr + k]) = l;
}

// ---------------- MFMA GEMMs ----------------

// enc_ctx = enc_bf @ W_enc_bf^T + b_enc -> bf16 [38400][1024], PAIRED column layout:
// column c stored at position (c<512) ? 2c : 2(c-512)+1  (uint holds {a, a+512})
__global__ __launch_bounds__(256) void mfma_encctx(const unsigned short* __restrict__ A,
                                                   const unsigned short* __restrict__ Bm,
                                                   const float* __restrict__ bias,
                                                   unsigned short* __restrict__ C) {
  __shared__ unsigned short sA[4096], sB[4096];
  constexpr int nbx = cA / 128;
  int bid = xcd_swizzle(blockIdx.x, gridDim.x);
  int by = bid / nbx, bx = bid % nbx;
  int tid = threadIdx.x;
  int w = tid >> 6, l = tid & 63;
  int m0 = by * 128, n0 = bx * 128;
  int wr = w >> 1, wc = w & 1;
  f32x4 acc[4][4] = {};
  int srow = tid >> 2, scol = (tid & 3) * 8;
  for (int k0 = 0; k0 < cD; k0 += 32) {
    __syncthreads();
    GLD(&A[(size_t)(m0 + srow) * cD + k0 + scol], &sA[tid * 8]);
    GLD(&A[(size_t)(m0 + 64 + srow) * cD + k0 + scol], &sA[2048 + tid * 8]);
    GLD(&Bm[(size_t)(n0 + srow) * cD + k0 + scol], &sB[tid * 8]);
    GLD(&Bm[(size_t)(n0 + 64 + srow) * cD + k0 + scol], &sB[2048 + tid * 8]);
    __syncthreads();
    int rA = wr * 64 + (l & 15);
    int rB = wc * 64 + (l & 15);
    int kg = (l >> 4) * 8;
    bf16x8 a[4], b[4];
#pragma unroll
    for (int i = 0; i < 4; ++i) a[i] = *(const bf16x8*)&sA[(rA + i * 16) * 32 + kg];
#pragma unroll
    for (int j = 0; j < 4; ++j) b[j] = *(const bf16x8*)&sB[(rB + j * 16) * 32 + kg];
#pragma unroll
    for (int i = 0; i < 4; ++i)
#pragma unroll
      for (int j = 0; j < 4; ++j)
        acc[i][j] = __builtin_amdgcn_mfma_f32_16x16x32_bf16(a[i], b[j], acc[i][j], 0, 0, 0);
  }
  int rbase = m0 + wr * 64 + ((l >> 4) * 4);
  int cbase = n0 + wc * 64 + (l & 15);
  float bv[4];
#pragma unroll
  for (int j = 0; j < 4; ++j) bv[j] = bias[cbase + j * 16];
#pragma unroll
  for (int i = 0; i < 4; ++i)
#pragma unroll
    for (int q = 0; q < 4; ++q) {
      int row = rbase + i * 16 + q;
#pragma unroll
      for (int j = 0; j < 4; ++j) {
        int col = cbase + j * 16;
        int pos = (col < 512) ? (2 * col) : (2 * (col - 512) + 1);
        C[(size_t)row * cA + pos] = f2bf(acc[i][j][q] + bv[j]);
      }
    }
}

template <int EP>
__global__ __launch_bounds__(256) void mfma_gemm3(
    const unsigned short* __restrict__ Ah, const unsigned short* __restrict__ Al,
    const unsigned short* __restrict__ Bh, const unsigned short* __restrict__ Bl,
    const float* __restrict__ bias, void* __restrict__ outv, int K, int nbx) {
  __shared__ unsigned short sAh[4096], sAl[4096], sBh[4096], sBl[4096];
  int bid = xcd_swizzle(blockIdx.x, gridDim.x);
  int by = bid / nbx, bx = bid % nbx;
  int tid = threadIdx.x;
  int w = tid >> 6, l = tid & 63;
  int m0 = by * 128, n0 = bx * 128;
  int wr = w >> 1, wc = w & 1;
  f32x4 acc[4][4] = {};
  int srow = tid >> 2, scol = (tid & 3) * 8;
  for (int k0 = 0; k0 < K; k0 += 32) {
    __syncthreads();
    GLD(&Ah[(size_t)(m0 + srow) * K + k0 + scol], &sAh[tid * 8]);
    GLD(&Ah[(size_t)(m0 + 64 + srow) * K + k0 + scol], &sAh[2048 + tid * 8]);
    GLD(&Al[(size_t)(m0 + srow) * K + k0 + scol], &sAl[tid * 8]);
    GLD(&Al[(size_t)(m0 + 64 + srow) * K + k0 + scol], &sAl[2048 + tid * 8]);
    GLD(&Bh[(size_t)(n0 + srow) * K + k0 + scol], &sBh[tid * 8]);
    GLD(&Bh[(size_t)(n0 + 64 + srow) * K + k0 + scol], &sBh[2048 + tid * 8]);
    GLD(&Bl[(size_t)(n0 + srow) * K + k0 + scol], &sBl[tid * 8]);
    GLD(&Bl[(size_t)(n0 + 64 + srow) * K + k0 + scol], &sBl[2048 + tid * 8]);
    __syncthreads();
    int rA = wr * 64 + (l & 15);
    int rB = wc * 64 + (l & 15);
    int kg = (l >> 4) * 8;
    bf16x8 bh[4], bl[4];
#pragma unroll
    for (int j = 0; j < 4; ++j) {
      bh[j] = *(const bf16x8*)&sBh[(rB + j * 16) * 32 + kg];
      bl[j] = *(const bf16x8*)&sBl[(rB + j * 16) * 32 + kg];
    }
#pragma unroll
    for (int i = 0; i < 4; ++i) {
      bf16x8 ah = *(const bf16x8*)&sAh[(rA + i * 16) * 32 + kg];
      bf16x8 al = *(const bf16x8*)&sAl[(rA + i * 16) * 32 + kg];
#pragma unroll
      for (int j = 0; j < 4; ++j) {
        acc[i][j] = __builtin_amdgcn_mfma_f32_16x16x32_bf16(ah, bh[j], acc[i][j], 0, 0, 0);
        acc[i][j] = __builtin_amdgcn_mfma_f32_16x16x32_bf16(ah, bl[j], acc[i][j], 0, 0, 0);
        acc[i][j] = __builtin_amdgcn_mfma_f32_16x16x32_bf16(al, bh[j], acc[i][j], 0, 0, 0);
        if (EP == 2)
          acc[i][j] = __builtin_amdgcn_mfma_f32_16x16x32_bf16(al, bl[j], acc[i][j], 0, 0, 0);
      }
    }
  }
  int rbase = m0 + wr * 64 + ((l >> 4) * 4);
  int cbase = n0 + wc * 64 + (l & 15);
  if (EP == 0) {
    unsigned short* mo_h = (unsigned short*)outv;
    unsigned short* mo_l = mo_h + (size_t)cM * (cP / 2);
#pragma unroll
    for (int i = 0; i < 4; ++i)
#pragma unroll
      for (int q = 0; q < 4; ++q) {
        int row = rbase + i * 16 + q;
#pragma unroll
        for (int j = 0; j < 4; ++j) {
          float v = acc[i][j][q] + bias[cbase + j * 16];
          float o = fmaxf(v, __shfl_xor(v, 1));
          if (!(l & 1)) {
            int ch = (cbase + j * 16) >> 1;
            unsigned short h = f2bf(o);
            mo_h[(size_t)row * (cP / 2) + ch] = h;
            mo_l[(size_t)row * (cP / 2) + ch] = f2bf(o - bfu(h));
          }
        }
      }
  } else if (EP == 1) {
    float* out = (float*)outv;
#pragma unroll
    for (int i = 0; i < 4; ++i)
#pragma unroll
      for (int q = 0; q < 4; ++q) {
        int row = rbase + i * 16 + q;
#pragma unroll
        for (int j = 0; j < 4; ++j) {
          int col = cbase + j * 16;
          if (col < cV) out[(size_t)row * cV + col] = acc[i][j][q] + bias[col];
        }
      }
  } else {
    float* out = (float*)outv;  // embg [4096 rows][3072]
#pragma unroll
    for (int i = 0; i < 4; ++i)
#pragma unroll
      for (int q = 0; q < 4; ++q) {
        int row = rbase + i * 16 + q;
#pragma unroll
        for (int j = 0; j < 4; ++j)
          out[(size_t)row * cG3 + cbase + j * 16] = acc[i][j][q];
      }
  }
}

// ---------------- split fused loop: 8 blocks/batch, GLD-staged streams ----------------

struct LoopArgs {
  const unsigned short* enc_ctx;  // bf16 [38400][1024] paired-column layout
  const unsigned short* enc_bf;   // bf16 [38400][512]
  const unsigned short* WihP;     // packed [128][3072][4] bf16 (k-major)
  const unsigned short* WsP;      // packed [256][1024][4] bf16 (k-major)
  const float* b_ih;
  const float* b_hh;
  const float* embg;              // fp32 [4096][3072]
  const float* inv_fert;          // [38400]
  const float* v_att;
  const float* W_fb;
  const int* slen;
  float* s_seq;                   // [4096][1024]
  float* ctx_seq;                 // [4096][512]
  float* xq;                      // [2][64][8][1024] q partials
  float* xc;                      // [2][64][8][516] softmax partials
  unsigned* cnt;                  // [2][64][64] arrival counters (256B stride)
};

__global__ __launch_bounds__(1024, 8)  // 8 waves/EU => 2 blocks/CU co-resident, VGPR<=64
void split_loop(LoopArgs A) {
  __shared__ float ctx_s[cD];
  __shared__ float h_s[128];       // own j-eighth of h
  __shared__ float q_s[cA];
  __shared__ float ew_s[cTE + 5];  // pads [75..79] stay 0
  __shared__ float acc_s[cTE];
  __shared__ float fert_s[cTE];
  __shared__ float vatt_s[cA];
  __shared__ float wfb_s[cA];
  __shared__ float cpartL[4][256];
  __shared__ float cpartH[4][256];
  __shared__ float red_s[16];
  __shared__ float ms_s[16];       // (m,s) of the 8 eighths
  __shared__ float rp2_s[2][8][2]; // per-chunk row partials (P3)
  __shared__ unsigned short ec_s[2][8192];  // 2 x 16KB staging ring

  const int od = blockIdx.x & 7;              // eighth 0..7
  const int b = blockIdx.x >> 3;              // batch 0..63
  const int tid = threadIdx.x;
  const int wv = tid >> 6, ln = tid & 63;     // 16 waves
  const int jl = tid >> 3, part = tid & 7;    // 128 j x 8 k-parts
  const int gp = tid >> 8, pp = tid & 255;    // P4: row-group x d-pair
  const int j0 = od * 128;
  const int len = A.slen[b];
  const int nv = (len - od + 7) >> 3;         // valid rows for this block (i < nv)
  unsigned* cntQ = A.cnt + (0 * cB + b) * 64;
  unsigned* cntS = A.cnt + (1 * cB + b) * 64;

  // init
  if (tid < cD) ctx_s[tid] = 0.f;
  vatt_s[tid] = A.v_att[tid];
  wfb_s[tid] = A.W_fb[tid];
  if (tid < cTE) {
    acc_s[tid] = 0.f;
    fert_s[tid] = A.inv_fert[b * cT + 8 * tid + od];
  }
  if (tid >= cTE && tid < cTE + 5) ew_s[tid] = 0.f;  // pads, never rewritten
  float h_my = 0.f, bgi = 0.f, bgg = 0.f, bgo = 0.f;
  if (part == 0) {
    int j = j0 + jl;
    bgi = A.b_ih[j] + A.b_hh[j];
    bgg = A.b_ih[j + 2048] + A.b_hh[j + 2048];
    bgo = A.b_ih[j + 3072] + A.b_hh[j + 3072];
  }
  __syncthreads();

  for (int t = 0; t < cN; ++t) {
    const int par = t & 1;
    const unsigned tgt = (unsigned)cNB * (t + 1);

    // ---- P1: h for j-eighth (8-lane k-split over 512 ctx dims) ----
    {
      float ai = 0.f, ag = 0.f, ao = 0.f;
      const unsigned short* wbase = A.WihP + (size_t)(j0 + jl) * 4;
#pragma unroll 4
      for (int k4 = 0; k4 < 16; ++k4) {
        int kk = (k4 + 2 * part) & 15;           // stagger: 2-way max on LDS banks
        int row = part * 16 + kk;
        float4 c = *reinterpret_cast<const float4*>(&ctx_s[row * 4]);
        const unsigned short* pw = wbase + (size_t)row * (cG3 * 4);
        ushort4 wi = *reinterpret_cast<const ushort4*>(pw);
        ushort4 wg = *reinterpret_cast<const ushort4*>(pw + (size_t)1024 * 4);
        ushort4 wo = *reinterpret_cast<const ushort4*>(pw + (size_t)2048 * 4);
        ai += bfu(wi.x) * c.x + bfu(wi.y) * c.y + bfu(wi.z) * c.z + bfu(wi.w) * c.w;
        ag += bfu(wg.x) * c.x + bfu(wg.y) * c.y + bfu(wg.z) * c.z + bfu(wg.w) * c.w;
        ao += bfu(wo.x) * c.x + bfu(wo.y) * c.y + bfu(wo.z) * c.z + bfu(wo.w) * c.w;
      }
      ai += __shfl_xor(ai, 1); ai += __shfl_xor(ai, 2); ai += __shfl_xor(ai, 4);
      ag += __shfl_xor(ag, 1); ag += __shfl_xor(ag, 2); ag += __shfl_xor(ag, 4);
      ao += __shfl_xor(ao, 1); ao += __shfl_xor(ao, 2); ao += __shfl_xor(ao, 4);
      if (part == 0) {
        int j = j0 + jl;
        const float* eg = A.embg + (size_t)(b * cN + t) * cG3;
        float gi = ai + bgi + eg[j];
        float gg = ag + bgg + eg[j + 1024];
        float go = ao + bgo + eg[j + 2048];
        float hnew = fsig(go) * ftanh(fsig(gi) * ftanh(gg));
        h_my = 0.05f * h_my + 0.95f * hnew;
        A.s_seq[(size_t)(b * cN + t) * cH + j] = h_my;
        h_s[jl] = h_my;
      }
    }
    __syncthreads();

    // ---- P2: partial q over ALL 1024 a from own 128-k slice ----
    {
      float aq = 0.f;
      const unsigned short* pw = A.WsP + ((size_t)(od * 32) * cA + tid) * 4;
#pragma unroll 8
      for (int kk = 0; kk < 32; ++kk) {
        float4 hh = *reinterpret_cast<const float4*>(&h_s[kk * 4]);
        ushort4 w = *reinterpret_cast<const ushort4*>(pw);
        aq += bfu(w.x) * hh.x + bfu(w.y) * hh.y + bfu(w.z) * hh.z + bfu(w.w) * hh.w;
        pw += (size_t)cA * 4;
      }
      ast(&A.xq[(((size_t)par * cB + b) * cNB + od) * cA + tid], aq);
    }
    // issue P3 chunk 0 staging (rows i=0..7) -- hides under the rendezvous
    {
      int r = tid >> 7;
      size_t gr = (size_t)b * cT + (size_t)8 * r + od;
      GLD(A.enc_ctx + gr * cA + (size_t)(tid & 127) * 8, &ec_s[0][tid * 8]);
    }
    arrive_wait(cntQ, tgt);
    {
      const float* xb = A.xq + ((size_t)par * cB + b) * cNB * cA;
      float s = 0.f;
#pragma unroll
      for (int o = 0; o < cNB; ++o) s += ald(&xb[o * cA + tid]);
      q_s[tid] = s;
    }
    __syncthreads();

    // ---- P3: energies via GLD-staged chunks (8 rows/chunk, 10 chunks) ----
    for (int c = 0; c < 10; ++c) {
      const int cur = c & 1;
      if (c < 9) {
        int r = tid >> 7;
        size_t gr = (size_t)b * cT + (size_t)8 * (8 * (c + 1) + r) + od;
        if (gr >= (size_t)cBT) gr = (size_t)cBT - 1;   // tail clamp (masked rows)
        GLD(A.enc_ctx + gr * cA + (size_t)(tid & 127) * 8, &ec_s[cur ^ 1][tid * 8]);
      }
      {
        int r = wv >> 1, hf = wv & 1;
        int i = 8 * c + r;
        float acc = 0.f;
        if (i < nv) {
          float fb = acc_s[i];
          const unsigned* rp = (const unsigned*)&ec_s[cur][r * 1024];
#pragma unroll
          for (int k2 = 0; k2 < 4; ++k2) {
            int a0 = hf * 256 + ln + 64 * k2;
            unsigned u = rp[a0];
            float c0 = __uint_as_float(u << 16);
            float c1 = __uint_as_float(u & 0xffff0000u);
            acc += vatt_s[a0] * ftanh(c0 + q_s[a0] + fb * wfb_s[a0]);
            acc += vatt_s[a0 + 512] * ftanh(c1 + q_s[a0 + 512] + fb * wfb_s[a0 + 512]);
          }
#pragma unroll
          for (int o = 32; o; o >>= 1) acc += __shfl_xor(acc, o);
        }
        if (ln == 0) rp2_s[cur][r][hf] = acc;
      }
      __syncthreads();   // drains prefetch of c+1; publishes rp2[cur]
      if (tid < 8) {
        int i = 8 * c + tid;
        if (i < cTE)
          ew_s[i] = (i < nv) ? (rp2_s[cur][tid][0] + rp2_s[cur][tid][1])
                             : -__builtin_inff();
      }
    }
    __syncthreads();

    // ---- local softmax over own rows ----
    // issue P4 chunk 0 staging (enc_bf rows i=0..15) -- hides under softmax
    {
      int rr = tid >> 6;
      size_t gr = (size_t)b * cT + (size_t)8 * rr + od;
      GLD(A.enc_bf + gr * cD + (size_t)(tid & 63) * 8, &ec_s[0][tid * 8]);
    }
    float m_loc;
    {
      float m = (tid < cTE) ? ew_s[tid] : -__builtin_inff();
#pragma unroll
      for (int o = 32; o; o >>= 1) m = fmaxf(m, __shfl_xor(m, o));
      if (ln == 0) red_s[wv] = m;
      __syncthreads();
      m = red_s[0];
#pragma unroll
      for (int w2 = 1; w2 < 16; ++w2) m = fmaxf(m, red_s[w2]);
      m_loc = m;
      __syncthreads();
      float wn = 0.f;
      if (tid < cTE) {
        float e = ew_s[tid];
        if (e > -__builtin_inff()) wn = __expf(e - m_loc);
        ew_s[tid] = wn;
      }
      float sp = wn;
#pragma unroll
      for (int o = 32; o; o >>= 1) sp += __shfl_xor(sp, o);
      if (ln == 0) red_s[wv] = sp;
      __syncthreads();
    }
    float s_loc = red_s[0];
#pragma unroll
    for (int w2 = 1; w2 < 16; ++w2) s_loc += red_s[w2];
    __syncthreads();

    // ---- P4: partial ctx via GLD-staged chunks (16 rows/chunk, 5 chunks) ----
    {
      float s0 = 0.f, s1 = 0.f;
      for (int c = 0; c < 5; ++c) {
        const int cur = c & 1;
        if (c < 4) {
          int rr = tid >> 6;
          size_t gr = (size_t)b * cT + (size_t)8 * (16 * (c + 1) + rr) + od;
          if (gr >= (size_t)cBT) gr = (size_t)cBT - 1;
          GLD(A.enc_bf + gr * cD + (size_t)(tid & 63) * 8, &ec_s[cur ^ 1][tid * 8]);
        }
#pragma unroll
        for (int l2 = 0; l2 < 4; ++l2) {
          int lr = gp + 4 * l2;
          int i = 16 * c + lr;
          if (i < nv) {
            float wgt = ew_s[i];
            unsigned u = ((const unsigned*)&ec_s[cur][lr * 512])[pp];
            s0 += wgt * __uint_as_float(u << 16);
            s1 += wgt * __uint_as_float(u & 0xffff0000u);
          }
        }
        __syncthreads();   // drains prefetch of c+1
      }
      cpartL[gp][pp] = s0;
      cpartH[gp][pp] = s1;
    }
    __syncthreads();
    {
      float* xcb = A.xc + (((size_t)par * cB + b) * cNB + od) * cXCS;
      if (tid < cD) {
        int p2 = tid >> 1;
        float v = (tid & 1)
                      ? (cpartH[0][p2] + cpartH[1][p2] + cpartH[2][p2] + cpartH[3][p2])
                      : (cpartL[0][p2] + cpartL[1][p2] + cpartL[2][p2] + cpartL[3][p2]);
        ast(&xcb[2 + tid], v);
      }
      if (tid == 0) ast(&xcb[0], m_loc);
      if (tid == 1) ast(&xcb[1], s_loc);
    }
    arrive_wait(cntS, tgt);

    // ---- combine: M, tot, full ctx; accum update ----
    if (tid < 16) {
      ms_s[tid] =
          ald(&A.xc[(((size_t)par * cB + b) * cNB + (tid >> 1)) * cXCS + (tid & 1)]);
    }
    __syncthreads();
    {
      float M = -__builtin_inff();
#pragma unroll
      for (int o = 0; o < cNB; ++o) M = fmaxf(M, ms_s[2 * o]);
      float tot = 0.f;
      float sc[cNB];
#pragma unroll
      for (int o = 0; o < cNB; ++o) {
        sc[o] = __expf(ms_s[2 * o] - M);
        tot += ms_s[2 * o + 1] * sc[o];
      }
      float invt = 1.0f / tot;
      if (tid < cD) {
        const float* xcb = A.xc + ((size_t)par * cB + b) * cNB * cXCS;
        float cv = 0.f;
#pragma unroll
        for (int o = 0; o < cNB; ++o) cv += ald(&xcb[o * cXCS + 2 + tid]) * sc[o];
        cv *= invt;
        ctx_s[tid] = cv;
        if (od == 0) A.ctx_seq[(size_t)(b * cN + t) * cD + tid] = cv;
      } else {
        int i = tid - 512;
        if (i < cTE) {
          float scq = __expf(m_loc - M);
          acc_s[i] += ew_s[i] * scq * invt * fert_s[i] * 0.5f;
        }
      }
    }
    __syncthreads();
  }
}

// ---------------- launcher ----------------

extern "C" void kernel_launch(void* const* d_in, const int* in_sizes, int n_in,
                              void* d_out, int out_size, void* d_ws, size_t ws_size,
                              hipStream_t stream) {
  (void)in_sizes; (void)n_in; (void)out_size; (void)ws_size;
  const float* enc    = (const float*)d_in[0];
  const int*   labels = (const int*)d_in[1];
  const int*   slen   = (const int*)d_in[2];
  const float* embed  = (const float*)d_in[3];
  const float* W_ih   = (const float*)d_in[4];
  const float* b_ih   = (const float*)d_in[5];
  const float* b_hh   = (const float*)d_in[6];
  const float* W_s    = (const float*)d_in[7];
  const float* W_enc  = (const float*)d_in[8];
  const float* b_enc  = (const float*)d_in[9];
  const float* v_att  = (const float*)d_in[10];
  const float* W_fert = (const float*)d_in[11];
  const float* W_fb   = (const float*)d_in[12];
  const float* W_r    = (const float*)d_in[13];
  const float* b_r    = (const float*)d_in[14];
  const float* W_o    = (const float*)d_in[15];
  const float* b_o    = (const float*)d_in[16];
  float* out = (float*)d_out;

  char* ws = (char*)d_ws;
  size_t off = 0;
  auto alloc = [&](size_t bytes) -> char* {
    char* p = ws + off;
    off = (off + bytes + 255) & ~(size_t)255;
    return p;
  };
  unsigned short* enc_ctx = (unsigned short*)alloc((size_t)cBT * cA * 2);
  unsigned short* enc_bf  = (unsigned short*)alloc((size_t)cBT * cD * 2);
  unsigned short* wencb   = (unsigned short*)alloc((size_t)cA * cD * 2);
  float* inv_fert = (float*)alloc((size_t)cBT * 4);
  unsigned short* WihP = (unsigned short*)alloc((size_t)cD * cG3 * 2);
  unsigned short* WsP  = (unsigned short*)alloc((size_t)cH * cA * 2);
  float* embg     = (float*)alloc((size_t)cM * cG3 * 4);
  float* s_seq    = (float*)alloc((size_t)cM * cH * 4);
  float* ctx_seq  = (float*)alloc((size_t)cM * cD * 4);
  float* xq       = (float*)alloc((size_t)2 * cB * cNB * cA * 4);
  float* xc       = (float*)alloc((size_t)2 * cB * cNB * cXCS * 4);
  unsigned* cnt   = (unsigned*)alloc((size_t)2 * cB * 64 * 4);
  unsigned short* Aemb_h = (unsigned short*)alloc((size_t)cM * cE * 2);
  unsigned short* Aemb_l = (unsigned short*)alloc((size_t)cM * cE * 2);
  unsigned short* Wihe_h = (unsigned short*)alloc((size_t)cG3 * cE * 2);
  unsigned short* Wihe_l = (unsigned short*)alloc((size_t)cG3 * cE * 2);
  unsigned short* Ar_h = (unsigned short*)alloc((size_t)cM * cKr * 2);
  unsigned short* Ar_l = (unsigned short*)alloc((size_t)cM * cKr * 2);
  unsigned short* Wr_h = (unsigned short*)alloc((size_t)cP * cKr * 2);
  unsigned short* Wr_l = (unsigned short*)alloc((size_t)cP * cKr * 2);
  unsigned short* mo_hl = (unsigned short*)alloc((size_t)2 * cM * (cP / 2) * 2);
  unsigned short* Wo_h = (unsigned short*)alloc((size_t)cVp * cD * 2);
  unsigned short* Wo_l = (unsigned short*)alloc((size_t)cVp * cD * 2);

  hipMemsetAsync(cnt, 0, (size_t)2 * cB * 64 * 4, stream);

  cast_kernel<<<(cBT * cD) / 1024, 256, 0, stream>>>(enc, enc_bf);
  cast_kernel<<<(cA * cD) / 1024, 256, 0, stream>>>(W_enc, wencb);
  fert_kernel<<<cBT / 4, 256, 0, stream>>>(enc, W_fert, inv_fert);
  mfma_encctx<<<(cBT / 128) * (cA / 128), 256, 0, stream>>>(enc_bf, wencb, b_enc, enc_ctx);
  build_aemb<<<(cM * cE / 4) / 256, 256, 0, stream>>>(embed, labels, Aemb_h, Aemb_l);
  cast_wihe<<<(cG3 * cE / 4) / 256, 256, 0, stream>>>(W_ih, Wihe_h, Wihe_l);
  pack_wih<<<(cG3 * (cD / 4)) / 256, 256, 0, stream>>>(W_ih, WihP);
  pack_ws<<<(cA * (cH / 4)) / 256, 256, 0, stream>>>(W_s, WsP);
  cast_hl_kernel<<<(cP * cKr) / 1024, 256, 0, stream>>>(W_r, Wr_h, Wr_l);
  cast_wo_kernel<<<(cVp * cD) / 1024, 256, 0, stream>>>(W_o, Wo_h, Wo_l);
  mfma_gemm3<2><<<(cM / 128) * (cG3 / 128), 256, 0, stream>>>(
      Aemb_h, Aemb_l, Wihe_h, Wihe_l, nullptr, (void*)embg, cE, cG3 / 128);

  LoopArgs la;
  la.enc_ctx = enc_ctx; la.enc_bf = enc_bf; la.WihP = WihP; la.WsP = WsP;
  la.b_ih = b_ih; la.b_hh = b_hh; la.embg = embg; la.inv_fert = inv_fert;
  la.v_att = v_att; la.W_fb = W_fb; la.slen = slen;
  la.s_seq = s_seq; la.ctx_seq = ctx_seq;
  la.xq = xq; la.xc = xc; la.cnt = cnt;
  split_loop<<<dim3(cB * cNB), dim3(1024), 0, stream>>>(la);

  build_ar_kernel<<<(cM * cKr) / 1024, 256, 0, stream>>>(s_seq, ctx_seq, embed, labels,
                                                         Ar_h, Ar_l);
  mfma_gemm3<0><<<(cM / 128) * (cP / 128), 256, 0, stream>>>(Ar_h, Ar_l, Wr_h, Wr_l, b_r,
                                                             (void*)mo_hl, cKr, cP / 128);
  unsigned short* mo_h = mo_hl;
  unsigned short* mo_l = mo_hl + (size_t)cM * (cP / 2);
  mfma_gemm3<1><<<(cM / 128) * (cVp / 128), 256, 0, stream>>>(mo_h, mo_l, Wo_h, Wo_l, b_o,
                                                              (void*)out, cP / 2, cVp / 128);
}

// Round 16
// 6886.318 us; speedup vs baseline: 1.1237x; 1.0557x over previous
//
#include <hip/hip_runtime.h>
#include <math.h>

constexpr int cB = 64, cT = 600, cD = 512, cE = 640, cH = 1024, cA = 1024,
              cP = 1024, cV = 10025, cN = 64;
constexpr int cBT = cB * cT;       // 38400
constexpr int cKr = cH + cE + cD;  // 2176
constexpr int cM  = cB * cN;       // 4096
constexpr int cVp = 10112;         // V padded to 79*128
constexpr int cG3 = 3 * cH;        // 3072 (i,g,o)
constexpr int cTE = cT / 8;        // 75 rows per block (interleaved: tt = 8*i + od)
constexpr int cXCS = 516;          // xc stride: m, s, c[512], pad
constexpr int cNB = 8;             // blocks per batch

typedef __attribute__((ext_vector_type(8))) short bf16x8;
typedef __attribute__((ext_vector_type(4))) float f32x4;

__device__ __forceinline__ float bfu(unsigned short s) {
  return __uint_as_float(((unsigned int)s) << 16);
}
__device__ __forceinline__ unsigned short f2bf(float f) {
  unsigned int x = __float_as_uint(f);
  x += 0x7fffu + ((x >> 16) & 1u);
  return (unsigned short)(x >> 16);
}
__device__ __forceinline__ float fsig(float x) { return 1.0f / (1.0f + __expf(-x)); }
__device__ __forceinline__ float ftanh(float x) {
  float e = __expf(2.0f * x);
  return 1.0f - 2.0f / (e + 1.0f);
}

#define GLD(g, s)                                                          \
  __builtin_amdgcn_global_load_lds(                                       \
      (const __attribute__((address_space(1))) void*)(g),                 \
      (__attribute__((address_space(3))) void*)(s), 16, 0, 0)

__device__ __forceinline__ int xcd_swizzle(int bid, int nwg) {
  int q = nwg >> 3, r = nwg & 7;
  int x = bid & 7, loc = bid >> 3;
  return (x < r ? x * (q + 1) : r * (q + 1) + (x - r) * q) + loc;
}

// device-scope message passing (round-7-verified pattern)
__device__ __forceinline__ void ast(float* p, float v) {
  __hip_atomic_store(p, v, __ATOMIC_RELAXED, __HIP_MEMORY_SCOPE_AGENT);
}
__device__ __forceinline__ float ald(const float* p) {
  return __hip_atomic_load(p, __ATOMIC_RELAXED, __HIP_MEMORY_SCOPE_AGENT);
}
__device__ __forceinline__ void arrive_wait(unsigned* c, unsigned target) {
  __syncthreads();
  if (threadIdx.x == 0) {
    __hip_atomic_fetch_add(c, 1u, __ATOMIC_RELEASE, __HIP_MEMORY_SCOPE_AGENT);
    while (__hip_atomic_load(c, __ATOMIC_ACQUIRE, __HIP_MEMORY_SCOPE_AGENT) < target)
      __builtin_amdgcn_s_sleep(2);
  }
  __syncthreads();
}

// ---------------- precompute / casts ----------------

__global__ __launch_bounds__(256) void cast_kernel(const float* __restrict__ in,
                                                   unsigned short* __restrict__ out) {
  int i = blockIdx.x * 256 + threadIdx.x;
  float4 v = reinterpret_cast<const float4*>(in)[i];
  ushort4 o;
  o.x = f2bf(v.x); o.y = f2bf(v.y); o.z = f2bf(v.z); o.w = f2bf(v.w);
  reinterpret_cast<ushort4*>(out)[i] = o;
}

__global__ __launch_bounds__(256) void cast_hl_kernel(const float* __restrict__ in,
                                                      unsigned short* __restrict__ hi,
                                                      unsigned short* __restrict__ lo) {
  int i = blockIdx.x * 256 + threadIdx.x;
  float4 v = reinterpret_cast<const float4*>(in)[i];
  ushort4 h, l;
  h.x = f2bf(v.x); h.y = f2bf(v.y); h.z = f2bf(v.z); h.w = f2bf(v.w);
  l.x = f2bf(v.x - bfu(h.x)); l.y = f2bf(v.y - bfu(h.y));
  l.z = f2bf(v.z - bfu(h.z)); l.w = f2bf(v.w - bfu(h.w));
  reinterpret_cast<ushort4*>(hi)[i] = h;
  reinterpret_cast<ushort4*>(lo)[i] = l;
}

__global__ __launch_bounds__(256) void cast_wo_kernel(const float* __restrict__ in,
                                                      unsigned short* __restrict__ hi,
                                                      unsigned short* __restrict__ lo) {
  int idx = blockIdx.x * 256 + threadIdx.x;
  int row = idx >> 7;
  int k = (idx & 127) * 4;
  float4 v = (row < cV) ? *reinterpret_cast<const float4*>(&in[(size_t)row * cD + k])
                        : make_float4(0.f, 0.f, 0.f, 0.f);
  ushort4 h, l;
  h.x = f2bf(v.x); h.y = f2bf(v.y); h.z = f2bf(v.z); h.w = f2bf(v.w);
  l.x = f2bf(v.x - bfu(h.x)); l.y = f2bf(v.y - bfu(h.y));
  l.z = f2bf(v.z - bfu(h.z)); l.w = f2bf(v.w - bfu(h.w));
  reinterpret_cast<ushort4*>(hi)[idx] = h;
  reinterpret_cast<ushort4*>(lo)[idx] = l;
}

__global__ __launch_bounds__(256) void fert_kernel(const float* __restrict__ enc,
                                                   const float* __restrict__ W_fert,
                                                   float* __restrict__ inv_fert) {
  int wave = threadIdx.x >> 6, lane = threadIdx.x & 63;
  int row = blockIdx.x * 4 + wave;
  const float* r = enc + (size_t)row * cD;
  float s = 0.0f;
#pragma unroll
  for (int i = 0; i < 8; ++i) s += r[lane + 64 * i] * W_fert[lane + 64 * i];
#pragma unroll
  for (int o = 32; o; o >>= 1) s += __shfl_xor(s, o);
  if (lane == 0) inv_fert[row] = 1.0f / (1.0f + __expf(-s));
}

// shifted embeddings of labels -> hi/lo bf16 [4096][640]
__global__ __launch_bounds__(256) void build_aemb(const float* __restrict__ embed,
                                                  const int* __restrict__ labels,
                                                  unsigned short* __restrict__ Ah,
                                                  unsigned short* __restrict__ Al) {
  int idx = blockIdx.x * 256 + threadIdx.x;
  int row = idx / (cE / 4);
  int k = (idx % (cE / 4)) * 4;
  int b = row >> 6, tt = row & 63;
  float4 v = make_float4(0.f, 0.f, 0.f, 0.f);
  if (tt > 0) {
    int lab = labels[b * cN + tt - 1];
    v = *reinterpret_cast<const float4*>(&embed[(size_t)lab * cE + k]);
  }
  ushort4 h, l;
  h.x = f2bf(v.x); h.y = f2bf(v.y); h.z = f2bf(v.z); h.w = f2bf(v.w);
  l.x = f2bf(v.x - bfu(h.x)); l.y = f2bf(v.y - bfu(h.y));
  l.z = f2bf(v.z - bfu(h.z)); l.w = f2bf(v.w - bfu(h.w));
  *reinterpret_cast<ushort4*>(&Ah[(size_t)row * cE + k]) = h;
  *reinterpret_cast<ushort4*>(&Al[(size_t)row * cE + k]) = l;
}

// W_ih rows (i,g,o) x cols [0,640) -> hi/lo bf16 [3072][640] (for embg GEMM)
__global__ __launch_bounds__(256) void cast_wihe(const float* __restrict__ W_ih,
                                                 unsigned short* __restrict__ Wh,
                                                 unsigned short* __restrict__ Wl) {
  int idx = blockIdx.x * 256 + threadIdx.x;
  int jcol = idx / (cE / 4);
  int k = (idx % (cE / 4)) * 4;
  int r = (jcol < cH) ? jcol : jcol + cH;
  float4 v = *reinterpret_cast<const float4*>(&W_ih[(size_t)r * (cE + cD) + k]);
  ushort4 h, l;
  h.x = f2bf(v.x); h.y = f2bf(v.y); h.z = f2bf(v.z); h.w = f2bf(v.w);
  l.x = f2bf(v.x - bfu(h.x)); l.y = f2bf(v.y - bfu(h.y));
  l.z = f2bf(v.z - bfu(h.z)); l.w = f2bf(v.w - bfu(h.w));
  *reinterpret_cast<ushort4*>(&Wh[(size_t)jcol * cE + k]) = h;
  *reinterpret_cast<ushort4*>(&Wl[(size_t)jcol * cE + k]) = l;
}

// W_ih ctx-half -> packed k-major bf16: WihP[(k4*3072 + col)*4 + (k&3)]
__global__ __launch_bounds__(256) void pack_wih(const float* __restrict__ W_ih,
                                                unsigned short* __restrict__ WihP) {
  int idx = blockIdx.x * 256 + threadIdx.x;
  int col = idx >> 7;
  int k4 = idx & 127;
  int r = (col < cH) ? col : col + cH;
  float4 v = *reinterpret_cast<const float4*>(&W_ih[(size_t)r * (cE + cD) + cE + k4 * 4]);
  ushort4 h;
  h.x = f2bf(v.x); h.y = f2bf(v.y); h.z = f2bf(v.z); h.w = f2bf(v.w);
  *reinterpret_cast<ushort4*>(&WihP[((size_t)k4 * cG3 + col) * 4]) = h;
}

// W_s -> packed k-major bf16: WsP[(k4*1024 + a)*4 + (k&3)]
__global__ __launch_bounds__(256) void pack_ws(const float* __restrict__ W_s,
                                               unsigned short* __restrict__ WsP) {
  int idx = blockIdx.x * 256 + threadIdx.x;
  int a = idx >> 8;
  int k4 = idx & 255;
  float4 v = *reinterpret_cast<const float4*>(&W_s[(size_t)a * cH + k4 * 4]);
  ushort4 h;
  h.x = f2bf(v.x); h.y = f2bf(v.y); h.z = f2bf(v.z); h.w = f2bf(v.w);
  *reinterpret_cast<ushort4*>(&WsP[((size_t)k4 * cA + a) * 4]) = h;
}

// concat(s_seq, emb, ctx_seq) -> Ar hi/lo bf16 [4096][2176]
__global__ __launch_bounds__(256) void build_ar_kernel(
    const float* __restrict__ s_seq, const float* __restrict__ ctx_seq,
    const float* __restrict__ embed, const int* __restrict__ labels,
    unsigned short* __restrict__ Ah, unsigned short* __restrict__ Al) {
  int idx = blockIdx.x * 256 + threadIdx.x;
  int row = idx / (cKr / 4);
  int k = (idx % (cKr / 4)) * 4;
  int b = row >> 6, tt = row & 63;
  float4 v;
  if (k < cH) {
    v = *reinterpret_cast<const float4*>(&s_seq[(size_t)row * cH + k]);
  } else if (k < cH + cE) {
    if (tt == 0) {
      v = make_float4(0.f, 0.f, 0.f, 0.f);
    } else {
      int lab = labels[b * cN + tt - 1];
      v = *reinterpret_cast<const float4*>(&embed[(size_t)lab * cE + (k - cH)]);
    }
  } else {
    v = *reinterpret_cast<const float4*>(&ctx_seq[(size_t)row * cD + (k - cH - cE)]);
  }
  ushort4 h, l;
  h.x = f2bf(v.x); h.y = f2bf(v.y); h.z = f2bf(v.z); h.w = f2bf(v.w);
  l.x = f2bf(v.x - bfu(h.x)); l.y = f2bf(v.y - bfu(h.y));
  l.z = f2bf(v.z - bfu(h.z)); l.w = f2bf(v.w - bfu(h.w));
  *reinterpret_cast<ushort4*>(&Ah[(size_t)row * cKr + k]) = h;
  *reinterpret_cast<ushort4*>(&Al[(size_t)row * cKr + k]) = l;
}

// ---------------- MFMA GEMMs ----------------

// enc_ctx = enc_bf @ W_enc_bf^T + b_enc -> bf16 [38400][1024], PAIRED column layout:
// column c stored at position (c<512) ? 2c : 2(c-512)+1  (uint holds {a, a+512})
__global__ __launch_bounds__(256) void mfma_encctx(const unsigned short* __restrict__ A,
                                                   const unsigned short* __restrict__ Bm,
                                                   const float* __restrict__ bias,
                                                   unsigned short* __restrict__ C) {
  __shared__ unsigned short sA[4096], sB[4096];
  constexpr int nbx = cA / 128;
  int bid = xcd_swizzle(blockIdx.x, gridDim.x);
  int by = bid / nbx, bx = bid % nbx;
  int tid = threadIdx.x;
  int w = tid >> 6, l = tid & 63;
  int m0 = by * 128, n0 = bx * 128;
  int wr = w >> 1, wc = w & 1;
  f32x4 acc[4][4] = {};
  int srow = tid >> 2, scol = (tid & 3) * 8;
  for (int k0 = 0; k0 < cD; k0 += 32) {
    __syncthreads();
    GLD(&A[(size_t)(m0 + srow) * cD + k0 + scol], &sA[tid * 8]);
    GLD(&A[(size_t)(m0 + 64 + srow) * cD + k0 + scol], &sA[2048 + tid * 8]);
    GLD(&Bm[(size_t)(n0 + srow) * cD + k0 + scol], &sB[tid * 8]);
    GLD(&Bm[(size_t)(n0 + 64 + srow) * cD + k0 + scol], &sB[2048 + tid * 8]);
    __syncthreads();
    int rA = wr * 64 + (l & 15);
    int rB = wc * 64 + (l & 15);
    int kg = (l >> 4) * 8;
    bf16x8 a[4], b[4];
#pragma unroll
    for (int i = 0; i < 4; ++i) a[i] = *(const bf16x8*)&sA[(rA + i * 16) * 32 + kg];
#pragma unroll
    for (int j = 0; j < 4; ++j) b[j] = *(const bf16x8*)&sB[(rB + j * 16) * 32 + kg];
#pragma unroll
    for (int i = 0; i < 4; ++i)
#pragma unroll
      for (int j = 0; j < 4; ++j)
        acc[i][j] = __builtin_amdgcn_mfma_f32_16x16x32_bf16(a[i], b[j], acc[i][j], 0, 0, 0);
  }
  int rbase = m0 + wr * 64 + ((l >> 4) * 4);
  int cbase = n0 + wc * 64 + (l & 15);
  float bv[4];
#pragma unroll
  for (int j = 0; j < 4; ++j) bv[j] = bias[cbase + j * 16];
#pragma unroll
  for (int i = 0; i < 4; ++i)
#pragma unroll
    for (int q = 0; q < 4; ++q) {
      int row = rbase + i * 16 + q;
#pragma unroll
      for (int j = 0; j < 4; ++j) {
        int col = cbase + j * 16;
        int pos = (col < 512) ? (2 * col) : (2 * (col - 512) + 1);
        C[(size_t)row * cA + pos] = f2bf(acc[i][j][q] + bv[j]);
      }
    }
}

template <int EP>
__global__ __launch_bounds__(256) void mfma_gemm3(
    const unsigned short* __restrict__ Ah, const unsigned short* __restrict__ Al,
    const unsigned short* __restrict__ Bh, const unsigned short* __restrict__ Bl,
    const float* __restrict__ bias, void* __restrict__ outv, int K, int nbx) {
  __shared__ unsigned short sAh[4096], sAl[4096], sBh[4096], sBl[4096];
  int bid = xcd_swizzle(blockIdx.x, gridDim.x);
  int by = bid / nbx, bx = bid % nbx;
  int tid = threadIdx.x;
  int w = tid >> 6, l = tid & 63;
  int m0 = by * 128, n0 = bx * 128;
  int wr = w >> 1, wc = w & 1;
  f32x4 acc[4][4] = {};
  int srow = tid >> 2, scol = (tid & 3) * 8;
  for (int k0 = 0; k0 < K; k0 += 32) {
    __syncthreads();
    GLD(&Ah[(size_t)(m0 + srow) * K + k0 + scol], &sAh[tid * 8]);
    GLD(&Ah[(size_t)(m0 + 64 + srow) * K + k0 + scol], &sAh[2048 + tid * 8]);
    GLD(&Al[(size_t)(m0 + srow) * K + k0 + scol], &sAl[tid * 8]);
    GLD(&Al[(size_t)(m0 + 64 + srow) * K + k0 + scol], &sAl[2048 + tid * 8]);
    GLD(&Bh[(size_t)(n0 + srow) * K + k0 + scol], &sBh[tid * 8]);
    GLD(&Bh[(size_t)(n0 + 64 + srow) * K + k0 + scol], &sBh[2048 + tid * 8]);
    GLD(&Bl[(size_t)(n0 + srow) * K + k0 + scol], &sBl[tid * 8]);
    GLD(&Bl[(size_t)(n0 + 64 + srow) * K + k0 + scol], &sBl[2048 + tid * 8]);
    __syncthreads();
    int rA = wr * 64 + (l & 15);
    int rB = wc * 64 + (l & 15);
    int kg = (l >> 4) * 8;
    bf16x8 bh[4], bl[4];
#pragma unroll
    for (int j = 0; j < 4; ++j) {
      bh[j] = *(const bf16x8*)&sBh[(rB + j * 16) * 32 + kg];
      bl[j] = *(const bf16x8*)&sBl[(rB + j * 16) * 32 + kg];
    }
#pragma unroll
    for (int i = 0; i < 4; ++i) {
      bf16x8 ah = *(const bf16x8*)&sAh[(rA + i * 16) * 32 + kg];
      bf16x8 al = *(const bf16x8*)&sAl[(rA + i * 16) * 32 + kg];
#pragma unroll
      for (int j = 0; j < 4; ++j) {
        acc[i][j] = __builtin_amdgcn_mfma_f32_16x16x32_bf16(ah, bh[j], acc[i][j], 0, 0, 0);
        acc[i][j] = __builtin_amdgcn_mfma_f32_16x16x32_bf16(ah, bl[j], acc[i][j], 0, 0, 0);
        acc[i][j] = __builtin_amdgcn_mfma_f32_16x16x32_bf16(al, bh[j], acc[i][j], 0, 0, 0);
        if (EP == 2)
          acc[i][j] = __builtin_amdgcn_mfma_f32_16x16x32_bf16(al, bl[j], acc[i][j], 0, 0, 0);
      }
    }
  }
  int rbase = m0 + wr * 64 + ((l >> 4) * 4);
  int cbase = n0 + wc * 64 + (l & 15);
  if (EP == 0) {
    unsigned short* mo_h = (unsigned short*)outv;
    unsigned short* mo_l = mo_h + (size_t)cM * (cP / 2);
#pragma unroll
    for (int i = 0; i < 4; ++i)
#pragma unroll
      for (int q = 0; q < 4; ++q) {
        int row = rbase + i * 16 + q;
#pragma unroll
        for (int j = 0; j < 4; ++j) {
          float v = acc[i][j][q] + bias[cbase + j * 16];
          float o = fmaxf(v, __shfl_xor(v, 1));
          if (!(l & 1)) {
            int ch = (cbase + j * 16) >> 1;
            unsigned short h = f2bf(o);
            mo_h[(size_t)row * (cP / 2) + ch] = h;
            mo_l[(size_t)row * (cP / 2) + ch] = f2bf(o - bfu(h));
          }
        }
      }
  } else if (EP == 1) {
    float* out = (float*)outv;
#pragma unroll
    for (int i = 0; i < 4; ++i)
#pragma unroll
      for (int q = 0; q < 4; ++q) {
        int row = rbase + i * 16 + q;
#pragma unroll
        for (int j = 0; j < 4; ++j) {
          int col = cbase + j * 16;
          if (col < cV) out[(size_t)row * cV + col] = acc[i][j][q] + bias[col];
        }
      }
  } else {
    float* out = (float*)outv;  // embg [4096 rows][3072]
#pragma unroll
    for (int i = 0; i < 4; ++i)
#pragma unroll
      for (int q = 0; q < 4; ++q) {
        int row = rbase + i * 16 + q;
#pragma unroll
        for (int j = 0; j < 4; ++j)
          out[(size_t)row * cG3 + cbase + j * 16] = acc[i][j][q];
      }
  }
}

// ---------------- split fused loop: 8 blocks/batch, per-wave vmcnt pipelines ----------------

struct LoopArgs {
  const unsigned short* enc_ctx;  // bf16 [38400][1024] paired-column layout
  const unsigned short* enc_bf;   // bf16 [38400][512]
  const unsigned short* WihP;     // packed [128][3072][4] bf16 (k-major)
  const unsigned short* WsP;      // packed [256][1024][4] bf16 (k-major)
  const float* b_ih;
  const float* b_hh;
  const float* embg;              // fp32 [4096][3072]
  const float* inv_fert;          // [38400]
  const float* v_att;
  const float* W_fb;
  const int* slen;
  float* s_seq;                   // [4096][1024]
  float* ctx_seq;                 // [4096][512]
  float* xq;                      // [2][64][8][1024] q partials
  float* xc;                      // [2][64][8][516] softmax partials
  unsigned* cnt;                  // [2][64][64] arrival counters (256B stride)
};

__global__ __launch_bounds__(1024, 8)  // 8 waves/EU => 2 blocks/CU co-resident, VGPR<=64
void split_loop(LoopArgs A) {
  __shared__ float ctx_s[cD];
  __shared__ float h_s[128];       // own j-eighth of h
  __shared__ float q_s[cA];
  __shared__ float ew_s[cTE];
  __shared__ float acc_s[cTE];
  __shared__ float fert_s[cTE];
  __shared__ float vatt_s[cA];
  __shared__ float wfb_s[cA];
  __shared__ float red_s[16];
  __shared__ float ms_s[16];       // (m,s) of the 8 eighths
  // 64KB arena: P3 slots [16 waves][2][1024 shorts] (all 64KB);
  // P4 phase: cp float2[16][256] in lower 32KB, row slots [16][2][512] in upper 32KB.
  __shared__ __align__(16) unsigned short big_s[32768];

  const int od = blockIdx.x & 7;              // eighth 0..7
  const int b = blockIdx.x >> 3;              // batch 0..63
  const int tid = threadIdx.x;
  const int wv = tid >> 6, ln = tid & 63;     // 16 waves
  const int jl = tid >> 3, part = tid & 7;    // 128 j x 8 k-parts
  const int j0 = od * 128;
  const int len = A.slen[b];
  const int nv = (len - od + 7) >> 3;         // valid rows (i < nv); nv in [37,75]
  const int nr = (nv - wv + 15) >> 4;         // rows for this wave
  unsigned* cntQ = A.cnt + (0 * cB + b) * 64;
  unsigned* cntS = A.cnt + (1 * cB + b) * 64;

  // init
  if (tid < cD) ctx_s[tid] = 0.f;
  vatt_s[tid] = A.v_att[tid];
  wfb_s[tid] = A.W_fb[tid];
  if (tid < cTE) {
    acc_s[tid] = 0.f;
    fert_s[tid] = A.inv_fert[b * cT + 8 * tid + od];
  }
  float h_my = 0.f, bgi = 0.f, bgg = 0.f, bgo = 0.f;
  if (part == 0) {
    int j = j0 + jl;
    bgi = A.b_ih[j] + A.b_hh[j];
    bgg = A.b_ih[j + 2048] + A.b_hh[j + 2048];
    bgo = A.b_ih[j + 3072] + A.b_hh[j + 3072];
  }
  __syncthreads();

  for (int t = 0; t < cN; ++t) {
    const int par = t & 1;
    const unsigned tgt = (unsigned)cNB * (t + 1);

    // ---- P1: h for j-eighth (8-lane k-split over 512 ctx dims) ----
    {
      float ai = 0.f, ag = 0.f, ao = 0.f;
      const unsigned short* wbase = A.WihP + (size_t)(j0 + jl) * 4;
#pragma unroll 4
      for (int k4 = 0; k4 < 16; ++k4) {
        int kk = (k4 + 2 * part) & 15;           // stagger: 2-way max on LDS banks
        int row = part * 16 + kk;
        float4 c = *reinterpret_cast<const float4*>(&ctx_s[row * 4]);
        const unsigned short* pw = wbase + (size_t)row * (cG3 * 4);
        ushort4 wi = *reinterpret_cast<const ushort4*>(pw);
        ushort4 wg = *reinterpret_cast<const ushort4*>(pw + (size_t)1024 * 4);
        ushort4 wo = *reinterpret_cast<const ushort4*>(pw + (size_t)2048 * 4);
        ai += bfu(wi.x) * c.x + bfu(wi.y) * c.y + bfu(wi.z) * c.z + bfu(wi.w) * c.w;
        ag += bfu(wg.x) * c.x + bfu(wg.y) * c.y + bfu(wg.z) * c.z + bfu(wg.w) * c.w;
        ao += bfu(wo.x) * c.x + bfu(wo.y) * c.y + bfu(wo.z) * c.z + bfu(wo.w) * c.w;
      }
      ai += __shfl_xor(ai, 1); ai += __shfl_xor(ai, 2); ai += __shfl_xor(ai, 4);
      ag += __shfl_xor(ag, 1); ag += __shfl_xor(ag, 2); ag += __shfl_xor(ag, 4);
      ao += __shfl_xor(ao, 1); ao += __shfl_xor(ao, 2); ao += __shfl_xor(ao, 4);
      if (part == 0) {
        int j = j0 + jl;
        const float* eg = A.embg + (size_t)(b * cN + t) * cG3;
        float gi = ai + bgi + eg[j];
        float gg = ag + bgg + eg[j + 1024];
        float go = ao + bgo + eg[j + 2048];
        float hnew = fsig(go) * ftanh(fsig(gi) * ftanh(gg));
        h_my = 0.05f * h_my + 0.95f * hnew;
        A.s_seq[(size_t)(b * cN + t) * cH + j] = h_my;
        h_s[jl] = h_my;
      }
    }
    __syncthreads();

    // ---- P2: partial q over ALL 1024 a from own 128-k slice ----
    {
      float aq = 0.f;
      const unsigned short* pw = A.WsP + ((size_t)(od * 32) * cA + tid) * 4;
#pragma unroll 8
      for (int kk = 0; kk < 32; ++kk) {
        float4 hh = *reinterpret_cast<const float4*>(&h_s[kk * 4]);
        ushort4 w = *reinterpret_cast<const ushort4*>(pw);
        aq += bfu(w.x) * hh.x + bfu(w.y) * hh.y + bfu(w.z) * hh.z + bfu(w.w) * hh.w;
        pw += (size_t)cA * 4;
      }
      ast(&A.xq[(((size_t)par * cB + b) * cNB + od) * cA + tid], aq);
    }
    // issue this wave's P3 row 0 (slot 0) -- arrives during the rendezvous
    {
      const unsigned short* src = A.enc_ctx + ((size_t)b * cT + 8 * wv + od) * cA;
      unsigned short* dst = &big_s[wv * 2048];
      GLD(src + ln * 8, dst + ln * 8);
      GLD(src + 512 + ln * 8, dst + 512 + ln * 8);
    }
    arrive_wait(cntQ, tgt);
    {
      const float* xb = A.xq + ((size_t)par * cB + b) * cNB * cA;
      float s = 0.f;
#pragma unroll
      for (int o = 0; o < cNB; ++o) s += ald(&xb[o * cA + tid]);
      q_s[tid] = s;
    }
    __syncthreads();

    // ---- P3: per-wave pipelined energies (rows i = wv + 16*r), NO block barriers ----
    for (int r = 0; r < nr; ++r) {
      if (r + 1 < nr) {
        int i2 = wv + 16 * (r + 1);
        const unsigned short* src = A.enc_ctx + ((size_t)b * cT + 8 * i2 + od) * cA;
        unsigned short* dst = &big_s[wv * 2048 + ((r + 1) & 1) * 1024];
        GLD(src + ln * 8, dst + ln * 8);
        GLD(src + 512 + ln * 8, dst + 512 + ln * 8);
        asm volatile("s_waitcnt vmcnt(2)" ::: "memory");  // row r complete
      } else {
        asm volatile("s_waitcnt vmcnt(0)" ::: "memory");
      }
      int i = wv + 16 * r;
      float fb = acc_s[i];
      const unsigned* rp = (const unsigned*)&big_s[wv * 2048 + (r & 1) * 1024];
      float acc = 0.f;
#pragma unroll
      for (int k2 = 0; k2 < 8; ++k2) {
        unsigned u = rp[ln + 64 * k2];
        int a0 = ln + 64 * k2;
        float c0 = __uint_as_float(u << 16);
        float c1 = __uint_as_float(u & 0xffff0000u);
        acc += vatt_s[a0] * ftanh(c0 + q_s[a0] + fb * wfb_s[a0]);
        acc += vatt_s[a0 + 512] * ftanh(c1 + q_s[a0 + 512] + fb * wfb_s[a0 + 512]);
      }
#pragma unroll
      for (int o = 32; o; o >>= 1) acc += __shfl_xor(acc, o);
      if (ln == 0) ew_s[i] = acc;
    }
    if (nv + tid < cTE) ew_s[nv + tid] = -__builtin_inff();
    __syncthreads();

    // issue this wave's P4 row 0 (upper arena; all P3 reads are done) ----
    {
      const unsigned short* src = A.enc_bf + ((size_t)b * cT + 8 * wv + od) * cD;
      unsigned short* dst = &big_s[16384 + wv * 1024];
      GLD(src + ln * 8, dst + ln * 8);
    }

    // ---- local softmax over own rows ----
    float m_loc;
    {
      float m = (tid < cTE) ? ew_s[tid] : -__builtin_inff();
#pragma unroll
      for (int o = 32; o; o >>= 1) m = fmaxf(m, __shfl_xor(m, o));
      if (ln == 0) red_s[wv] = m;
      __syncthreads();
      m = red_s[0];
#pragma unroll
      for (int w2 = 1; w2 < 16; ++w2) m = fmaxf(m, red_s[w2]);
      m_loc = m;
      __syncthreads();
      float wn = 0.f;
      if (tid < cTE) {
        float e = ew_s[tid];
        if (e > -__builtin_inff()) wn = __expf(e - m_loc);
        ew_s[tid] = wn;
      }
      float sp = wn;
#pragma unroll
      for (int o = 32; o; o >>= 1) sp += __shfl_xor(sp, o);
      if (ln == 0) red_s[wv] = sp;
      __syncthreads();
    }
    float s_loc = red_s[0];
#pragma unroll
    for (int w2 = 1; w2 < 16; ++w2) s_loc += red_s[w2];
    __syncthreads();

    // ---- P4: per-wave pipelined ctx partials (rows i = wv + 16*r) ----
    {
      float s0[4] = {0.f, 0.f, 0.f, 0.f}, s1[4] = {0.f, 0.f, 0.f, 0.f};
      for (int r = 0; r < nr; ++r) {
        if (r + 1 < nr) {
          int i2 = wv + 16 * (r + 1);
          const unsigned short* src = A.enc_bf + ((size_t)b * cT + 8 * i2 + od) * cD;
          unsigned short* dst = &big_s[16384 + wv * 1024 + ((r + 1) & 1) * 512];
          GLD(src + ln * 8, dst + ln * 8);
          asm volatile("s_waitcnt vmcnt(1)" ::: "memory");
        } else {
          asm volatile("s_waitcnt vmcnt(0)" ::: "memory");
        }
        int i = wv + 16 * r;
        float wgt = ew_s[i];
        const unsigned* rp = (const unsigned*)&big_s[16384 + wv * 1024 + (r & 1) * 512];
#pragma unroll
        for (int k = 0; k < 4; ++k) {
          unsigned u = rp[ln + 64 * k];
          s0[k] += wgt * __uint_as_float(u << 16);
          s1[k] += wgt * __uint_as_float(u & 0xffff0000u);
        }
      }
      float2* cp = (float2*)big_s;
#pragma unroll
      for (int k = 0; k < 4; ++k)
        cp[wv * 256 + ln + 64 * k] = make_float2(s0[k], s1[k]);
    }
    __syncthreads();
    {
      float* xcb = A.xc + (((size_t)par * cB + b) * cNB + od) * cXCS;
      if (tid < cD) {
        const float2* cp = (const float2*)big_s;
        int j = tid >> 1;
        float v = 0.f;
#pragma unroll
        for (int w = 0; w < 16; ++w) {
          float2 p = cp[w * 256 + j];
          v += (tid & 1) ? p.y : p.x;
        }
        ast(&xcb[2 + tid], v);
      }
      if (tid == 0) ast(&xcb[0], m_loc);
      if (tid == 1) ast(&xcb[1], s_loc);
    }
    arrive_wait(cntS, tgt);

    // ---- combine: M, tot, full ctx; accum update ----
    if (tid < 16) {
      ms_s[tid] =
          ald(&A.xc[(((size_t)par * cB + b) * cNB + (tid >> 1)) * cXCS + (tid & 1)]);
    }
    __syncthreads();
    {
      float M = -__builtin_inff();
#pragma unroll
      for (int o = 0; o < cNB; ++o) M = fmaxf(M, ms_s[2 * o]);
      float tot = 0.f;
      float sc[cNB];
#pragma unroll
      for (int o = 0; o < cNB; ++o) {
        sc[o] = __expf(ms_s[2 * o] - M);
        tot += ms_s[2 * o + 1] * sc[o];
      }
      float invt = 1.0f / tot;
      if (tid < cD) {
        const float* xcb = A.xc + ((size_t)par * cB + b) * cNB * cXCS;
        float cv = 0.f;
#pragma unroll
        for (int o = 0; o < cNB; ++o) cv += ald(&xcb[o * cXCS + 2 + tid]) * sc[o];
        cv *= invt;
        ctx_s[tid] = cv;
        if (od == 0) A.ctx_seq[(size_t)(b * cN + t) * cD + tid] = cv;
      } else {
        int i = tid - 512;
        if (i < cTE) {
          float scq = __expf(m_loc - M);
          acc_s[i] += ew_s[i] * scq * invt * fert_s[i] * 0.5f;
        }
      }
    }
    __syncthreads();
  }
}

// ---------------- launcher ----------------

extern "C" void kernel_launch(void* const* d_in, const int* in_sizes, int n_in,
                              void* d_out, int out_size, void* d_ws, size_t ws_size,
                              hipStream_t stream) {
  (void)in_sizes; (void)n_in; (void)out_size; (void)ws_size;
  const float* enc    = (const float*)d_in[0];
  const int*   labels = (const int*)d_in[1];
  const int*   slen   = (const int*)d_in[2];
  const float* embed  = (const float*)d_in[3];
  const float* W_ih   = (const float*)d_in[4];
  const float* b_ih   = (const float*)d_in[5];
  const float* b_hh   = (const float*)d_in[6];
  const float* W_s    = (const float*)d_in[7];
  const float* W_enc  = (const float*)d_in[8];
  const float* b_enc  = (const float*)d_in[9];
  const float* v_att  = (const float*)d_in[10];
  const float* W_fert = (const float*)d_in[11];
  const float* W_fb   = (const float*)d_in[12];
  const float* W_r    = (const float*)d_in[13];
  const float* b_r    = (const float*)d_in[14];
  const float* W_o    = (const float*)d_in[15];
  const float* b_o    = (const float*)d_in[16];
  float* out = (float*)d_out;

  char* ws = (char*)d_ws;
  size_t off = 0;
  auto alloc = [&](size_t bytes) -> char* {
    char* p = ws + off;
    off = (off + bytes + 255) & ~(size_t)255;
    return p;
  };
  unsigned short* enc_ctx = (unsigned short*)alloc((size_t)cBT * cA * 2);
  unsigned short* enc_bf  = (unsigned short*)alloc((size_t)cBT * cD * 2);
  unsigned short* wencb   = (unsigned short*)alloc((size_t)cA * cD * 2);
  float* inv_fert = (float*)alloc((size_t)cBT * 4);
  unsigned short* WihP = (unsigned short*)alloc((size_t)cD * cG3 * 2);
  unsigned short* WsP  = (unsigned short*)alloc((size_t)cH * cA * 2);
  float* embg     = (float*)alloc((size_t)cM * cG3 * 4);
  float* s_seq    = (float*)alloc((size_t)cM * cH * 4);
  float* ctx_seq  = (float*)alloc((size_t)cM * cD * 4);
  float* xq       = (float*)alloc((size_t)2 * cB * cNB * cA * 4);
  float* xc       = (float*)alloc((size_t)2 * cB * cNB * cXCS * 4);
  unsigned* cnt   = (unsigned*)alloc((size_t)2 * cB * 64 * 4);
  unsigned short* Aemb_h = (unsigned short*)alloc((size_t)cM * cE * 2);
  unsigned short* Aemb_l = (unsigned short*)alloc((size_t)cM * cE * 2);
  unsigned short* Wihe_h = (unsigned short*)alloc((size_t)cG3 * cE * 2);
  unsigned short* Wihe_l = (unsigned short*)alloc((size_t)cG3 * cE * 2);
  unsigned short* Ar_h = (unsigned short*)alloc((size_t)cM * cKr * 2);
  unsigned short* Ar_l = (unsigned short*)alloc((size_t)cM * cKr * 2);
  unsigned short* Wr_h = (unsigned short*)alloc((size_t)cP * cKr * 2);
  unsigned short* Wr_l = (unsigned short*)alloc((size_t)cP * cKr * 2);
  unsigned short* mo_hl = (unsigned short*)alloc((size_t)2 * cM * (cP / 2) * 2);
  unsigned short* Wo_h = (unsigned short*)alloc((size_t)cVp * cD * 2);
  unsigned short* Wo_l = (unsigned short*)alloc((size_t)cVp * cD * 2);

  hipMemsetAsync(cnt, 0, (size_t)2 * cB * 64 * 4, stream);

  cast_kernel<<<(cBT * cD) / 1024, 256, 0, stream>>>(enc, enc_bf);
  cast_kernel<<<(cA * cD) / 1024, 256, 0, stream>>>(W_enc, wencb);
  fert_kernel<<<cBT / 4, 256, 0, stream>>>(enc, W_fert, inv_fert);
  mfma_encctx<<<(cBT / 128) * (cA / 128), 256, 0, stream>>>(enc_bf, wencb, b_enc, enc_ctx);
  build_aemb<<<(cM * cE / 4) / 256, 256, 0, stream>>>(embed, labels, Aemb_h, Aemb_l);
  cast_wihe<<<(cG3 * cE / 4) / 256, 256, 0, stream>>>(W_ih, Wihe_h, Wihe_l);
  pack_wih<<<(cG3 * (cD / 4)) / 256, 256, 0, stream>>>(W_ih, WihP);
  pack_ws<<<(cA * (cH / 4)) / 256, 256, 0, stream>>>(W_s, WsP);
  cast_hl_kernel<<<(cP * cKr) / 1024, 256, 0, stream>>>(W_r, Wr_h, Wr_l);
  cast_wo_kernel<<<(cVp * cD) / 1024, 256, 0, stream>>>(W_o, Wo_h, Wo_l);
  mfma_gemm3<2><<<(cM / 128) * (cG3 / 128), 256, 0, stream>>>(
      Aemb_h, Aemb_l, Wihe_h, Wihe_l, nullptr, (void*)embg, cE, cG3 / 128);

  LoopArgs la;
  la.enc_ctx = enc_ctx; la.enc_bf = enc_bf; la.WihP = WihP; la.WsP = WsP;
  la.b_ih = b_ih; la.b_hh = b_hh; la.embg = embg; la.inv_fert = inv_fert;
  la.v_att = v_att; la.W_fb = W_fb; la.slen = slen;
  la.s_seq = s_seq; la.ctx_seq = ctx_seq;
  la.xq = xq; la.xc = xc; la.cnt = cnt;
  split_loop<<<dim3(cB * cNB), dim3(1024), 0, stream>>>(la);

  build_ar_kernel<<<(cM * cKr) / 1024, 256, 0, stream>>>(s_seq, ctx_seq, embed, labels,
                                                         Ar_h, Ar_l);
  mfma_gemm3<0><<<(cM / 128) * (cP / 128), 256, 0, stream>>>(Ar_h, Ar_l, Wr_h, Wr_l, b_r,
                                                             (void*)mo_hl, cKr, cP / 128);
  unsigned short* mo_h = mo_hl;
  unsigned short* mo_l = mo_hl + (size_t)cM * (cP / 2);
  mfma_gemm3<1><<<(cM / 128) * (cVp / 128), 256, 0, stream>>>(mo_h, mo_l, Wo_h, Wo_l, b_o,
                                                              (void*)out, cP / 2, cVp / 128);
}